// Round 6
// baseline (556.392 us; speedup 1.0000x reference)
//
#include <hip/hip_runtime.h>
#include <hip/hip_bf16.h>
#include <math.h>

#define NN 32768
#define EE 524288
#define LL 6

typedef __attribute__((ext_vector_type(8))) short short8;
typedef __attribute__((ext_vector_type(4))) float floatx4;

union U16x8 { short8 v; unsigned short u[8]; };

__device__ __forceinline__ unsigned short f2bf(float x) {
    union { float f; unsigned int u; } v; v.f = x;
    unsigned int r = v.u + 0x7fffu + ((v.u >> 16) & 1u);
    return (unsigned short)(r >> 16);
}
__device__ __forceinline__ float bf2f(unsigned short h) {
    union { unsigned int u; float f; } v; v.u = (unsigned int)h << 16;
    return v.f;
}

// ---------------- preprocessing ----------------

__global__ void deg_kernel(const int* __restrict__ dst, int* __restrict__ deg) {
    int e = blockIdx.x * 256 + threadIdx.x;
    if (e < EE) atomicAdd(&deg[dst[e]], 1);
}

__global__ __launch_bounds__(1024) void scan_kernel(const int* __restrict__ deg,
                                                    int* __restrict__ row_ptr) {
    __shared__ int bs[1024];
    int t = threadIdx.x;
    int base = t * 32;
    int loc[32];
    int s = 0;
#pragma unroll
    for (int i = 0; i < 32; ++i) { int v = deg[base + i]; loc[i] = s; s += v; }
    bs[t] = s;
    __syncthreads();
    for (int off = 1; off < 1024; off <<= 1) {
        int v = (t >= off) ? bs[t - off] : 0;
        __syncthreads();
        bs[t] += v;
        __syncthreads();
    }
    int pre = (t == 0) ? 0 : bs[t - 1];
#pragma unroll
    for (int i = 0; i < 32; ++i) row_ptr[base + i] = pre + loc[i];
    if (t == 1023) row_ptr[NN] = bs[1023];
}

__global__ void fill_kernel(const int* __restrict__ src, const int* __restrict__ dst,
                            const int* __restrict__ row_ptr, int* __restrict__ cnt,
                            int2* __restrict__ sedge) {
    int e = blockIdx.x * 256 + threadIdx.x;
    if (e >= EE) return;
    int d = dst[e];
    int pos = row_ptr[d] + atomicAdd(&cnt[d], 1);
    sedge[pos] = make_int2(src[e], e);
}

// v[l][ed][h] = sum_c lin_edge_W[l][ed][h*64+c] * att_edge[l][h][c]
__global__ void vmake_kernel(const float* __restrict__ lin_edge_W,
                             const float* __restrict__ att_edge,
                             float* __restrict__ v) {
    int t = threadIdx.x;
    if (t >= 384) return;
    int l = t >> 6; int r = t & 63; int ed = r >> 1; int hh = r & 1;
    const float* w = lin_edge_W + l * 32 * 128 + ed * 128 + hh * 64;
    const float* a = att_edge + l * 128 + hh * 64;
    float s = 0.f;
#pragma unroll 8
    for (int c = 0; c < 64; ++c) s += w[c] * a[c];
    v[t] = s;
}

// vs[l][h*64+k] = sum_c lin_W[l][k][h*64+c]*att_src[l][h][c]; vvd same with att_dst
__global__ void vsmake_kernel(const float* __restrict__ lin_W,
                              const float* __restrict__ att_src,
                              const float* __restrict__ att_dst,
                              float* __restrict__ vs, float* __restrict__ vvd) {
    int l = blockIdx.x;
    int tid = threadIdx.x;
    int sel = tid >> 7, idx = tid & 127;
    int h = idx >> 6, k = idx & 63;
    const float* att = (sel ? att_dst : att_src) + l * 128 + h * 64;
    const float* wr = lin_W + ((size_t)l * 64 + k) * 128 + h * 64;
    float s = 0.f;
#pragma unroll 8
    for (int c = 0; c < 64; ++c) s += wr[c] * att[c];
    (sel ? vvd : vs)[l * 128 + idx] = s;
}

// a_e for real edges, all layers, CSR-sorted order
__global__ void ae_kernel(const float* __restrict__ edge_attr,
                          const int2* __restrict__ sedge,
                          const float* __restrict__ v,
                          float* __restrict__ a_e_sorted) {
    __shared__ float sv[384];
    int tid = threadIdx.x;
    for (int i = tid; i < 384; i += 128) sv[i] = v[i];
    __syncthreads();
    int pos = blockIdx.x * 128 + tid;
    if (pos >= EE) return;
    int eid = sedge[pos].y;
    float ea[32];
    const float4* p = (const float4*)(edge_attr + (size_t)eid * 32);
#pragma unroll
    for (int i = 0; i < 8; ++i) {
        float4 f = p[i];
        ea[4 * i] = f.x; ea[4 * i + 1] = f.y; ea[4 * i + 2] = f.z; ea[4 * i + 3] = f.w;
    }
#pragma unroll
    for (int l = 0; l < LL; ++l) {
        float s0 = 0.f, s1 = 0.f;
#pragma unroll
        for (int ed = 0; ed < 32; ++ed) {
            float e = ea[ed];
            s0 += e * sv[l * 64 + ed * 2];
            s1 += e * sv[l * 64 + ed * 2 + 1];
        }
        a_e_sorted[((size_t)l * EE + pos) * 2] = s0;
        a_e_sorted[((size_t)l * EE + pos) * 2 + 1] = s1;
    }
}

// a_e_self[l][n] = mean over in-edges of a_e_sorted[l]
__global__ __launch_bounds__(256) void aeself_kernel(const float* __restrict__ a_e_sorted,
                                                     const int* __restrict__ row_ptr,
                                                     float* __restrict__ a_e_self) {
    int w = threadIdx.x >> 6, lane = threadIdx.x & 63;
    int n = blockIdx.x * 4 + w;
    int beg = row_ptr[n], end = row_ptr[n + 1];
    float invd = 1.f / fmaxf((float)(end - beg), 1.f);
    const float2* ae2 = (const float2*)a_e_sorted;
#pragma unroll
    for (int l = 0; l < LL; ++l) {
        float sx = 0.f, sy = 0.f;
        for (int i = beg + lane; i < end; i += 64) {
            float2 vv = ae2[(size_t)l * EE + i];
            sx += vv.x; sy += vv.y;
        }
        for (int off = 1; off < 64; off <<= 1) {
            sx += __shfl_xor(sx, off);
            sy += __shfl_xor(sy, off);
        }
        if (lane == 0) {
            a_e_self[((size_t)l * NN + n) * 2] = sx * invd;
            a_e_self[((size_t)l * NN + n) * 2 + 1] = sy * invd;
        }
    }
}

// embed + layer-0 LN/affine + layer-0 attention dots. 4 nodes/block, 1 wave/node.
__global__ __launch_bounds__(256) void embed_ln_kernel(
    const float* __restrict__ x, const float* __restrict__ W, const float* __restrict__ b,
    const float* __restrict__ ln_g, const float* __restrict__ ln_b,
    const float* __restrict__ mg, const float* __restrict__ mb,
    const float* __restrict__ vs0, const float* __restrict__ vd0,
    unsigned short* __restrict__ hm_bf, float* __restrict__ a_s, float* __restrict__ a_d) {
    __shared__ float xr[4][64];
    int w = threadIdx.x >> 6, j = threadIdx.x & 63;
    int n = blockIdx.x * 4 + w;
    xr[w][j] = x[(size_t)n * 64 + j];
    __syncthreads();
    float acc = b[j];
#pragma unroll 8
    for (int k = 0; k < 64; ++k) acc += xr[w][k] * W[k * 64 + j];
    // LN over the wave
    float s = acc, sq = acc * acc;
    for (int off = 1; off < 64; off <<= 1) { s += __shfl_xor(s, off); sq += __shfl_xor(sq, off); }
    float mu = s * (1.f / 64.f);
    float var = sq * (1.f / 64.f) - mu * mu;
    float rs = rsqrtf(var + 1e-5f);
    float hm = mg[j] * (ln_g[j] * (acc - mu) * rs + ln_b[j]) + mb[j];
    hm_bf[(size_t)n * 64 + j] = f2bf(hm);
    float s0 = hm * vs0[j], s1 = hm * vs0[64 + j];
    float d0 = hm * vd0[j], d1 = hm * vd0[64 + j];
    for (int off = 1; off < 64; off <<= 1) {
        s0 += __shfl_xor(s0, off); s1 += __shfl_xor(s1, off);
        d0 += __shfl_xor(d0, off); d1 += __shfl_xor(d1, off);
    }
    if (j == 0) {
        a_s[n * 2] = s0; a_s[n * 2 + 1] = s1;
        a_d[n * 2] = d0; a_d[n * 2 + 1] = d1;
    }
}

// Pre-swizzled bf16 hi/lo B tiles.
// blocks 0..5: Bmat[l]: [j=h*64+k][c] = 0.5*lin_W[l][k][h*64+c], stored [c][128 k-swizzled]
// block 6: uv tile, old layout [n 0..127][64 k-swizzled] = [W1a | W1b]
__global__ __launch_bounds__(256) void wprep_kernel(const float* __restrict__ lin_W,
                                                    const float* __restrict__ head_W1,
                                                    unsigned short* __restrict__ gBhi,
                                                    unsigned short* __restrict__ gBlo) {
    int bb = blockIdx.x;
    int tid = threadIdx.x;
    unsigned short* dh = gBhi + (size_t)bb * 128 * 64;
    unsigned short* dl = gBlo + (size_t)bb * 128 * 64;
    if (bb < 6) {
        int n2 = tid & 63, kh = tid >> 6;  // kh 0..3, each covers 32 j
        U16x8 hh[4], ll[4];
        for (int kk = 0; kk < 32; ++kk) {
            int j = kh * 32 + kk;
            int h = j >> 6, k = j & 63;
            float wv = 0.5f * lin_W[((size_t)bb * 64 + k) * 128 + h * 64 + n2];
            unsigned short h16 = f2bf(wv);
            hh[kk >> 3].u[kk & 7] = h16;
            ll[kk >> 3].u[kk & 7] = f2bf(wv - bf2f(h16));
        }
#pragma unroll
        for (int c = 0; c < 4; ++c) {
            int cg = kh * 4 + c;
            int off = n2 * 128 + ((cg ^ (n2 & 15)) << 3);
            *(short8*)(dh + off) = hh[c].v;
            *(short8*)(dl + off) = ll[c].v;
        }
    } else {
        int n = tid & 127, kh = tid >> 7;
        U16x8 hh[4], ll[4];
        for (int kk = 0; kk < 32; ++kk) {
            int k = kh * 32 + kk;
            float wv = (n < 64) ? head_W1[k * 64 + n] : head_W1[(64 + k) * 64 + (n - 64)];
            unsigned short h16 = f2bf(wv);
            hh[kk >> 3].u[kk & 7] = h16;
            ll[kk >> 3].u[kk & 7] = f2bf(wv - bf2f(h16));
        }
#pragma unroll
        for (int c = 0; c < 4; ++c) {
            int cg = kh * 4 + c;
            int off = n * 64 + ((cg ^ (n & 7)) << 3);
            *(short8*)(dh + off) = hh[c].v;
            *(short8*)(dl + off) = ll[c].v;
        }
    }
}

// ---------------- GAT aggregation v4: gather hm (128 B rows), 8 edges in flight ----------------
__device__ __forceinline__ void fma8(uint4 pv, float w0, float w1, float* a0, float* a1) {
    unsigned int u[4] = {pv.x, pv.y, pv.z, pv.w};
#pragma unroll
    for (int j = 0; j < 4; ++j) {
        union { unsigned int q; float f; } lo, hi;
        lo.q = u[j] << 16; hi.q = u[j] & 0xffff0000u;
        a0[2 * j] += w0 * lo.f;  a1[2 * j] += w1 * lo.f;
        a0[2 * j + 1] += w0 * hi.f;  a1[2 * j + 1] += w1 * hi.f;
    }
}

__global__ __launch_bounds__(256) void aggregate4_kernel(
    const unsigned short* __restrict__ hm_bf, const float* __restrict__ a_s,
    const float* __restrict__ a_d, const float* __restrict__ a_e_sorted,
    const float* __restrict__ a_e_self, const int* __restrict__ row_ptr,
    const int2* __restrict__ sedge, float* __restrict__ S) {
    __shared__ float2 swg[4][64];
    __shared__ int ssv[4][64];
    int w = threadIdx.x >> 6, lane = threadIdx.x & 63;
    int n = blockIdx.x * 4 + w;
    int slot = lane >> 3, ch = lane & 7;
    const float2* as2 = (const float2*)a_s;
    const uint4* hmv = (const uint4*)hm_bf;  // 8 uint4 per 64-ch row
    float2 adn = ((const float2*)a_d)[n];
    float2 asn = as2[n];
    float2 aes = ((const float2*)a_e_self)[n];
    uint4 pvself = hmv[(size_t)n * 8 + ch];  // hoisted self row chunk
    int beg = row_ptr[n], end = row_ptr[n + 1];

    float acc0[8] = {}, acc1[8] = {};
    float den0 = 0.f, den1 = 0.f;

    for (int cs = beg; cs < end; cs += 64) {
        int cnt = min(64, end - cs);
        float2 wpair = make_float2(0.f, 0.f);
        int sval = n;
        if (lane < cnt) {
            int2 se = sedge[cs + lane];
            float2 ae = ((const float2*)a_e_sorted)[cs + lane];
            float2 as = as2[se.x];
            float al0 = as.x + adn.x + ae.x; al0 = al0 > 0.f ? al0 : 0.2f * al0;
            float al1 = as.y + adn.y + ae.y; al1 = al1 > 0.f ? al1 : 0.2f * al1;
            wpair = make_float2(__expf(al0), __expf(al1));
            sval = se.x;
        }
        swg[w][lane] = wpair;
        ssv[w][lane] = sval;
        // per-wave produce->consume (lgkmcnt, no barrier needed)
        int ng2 = (cnt + 15) >> 4;
        for (int g2 = 0; g2 < ng2; ++g2) {
            int eA = g2 * 16 + slot, eB = g2 * 16 + 8 + slot;
            float2 wA = swg[w][eA];
            float2 wB = swg[w][eB];
            int svA = ssv[w][eA];
            int svB = ssv[w][eB];
            uint4 pvA = hmv[(size_t)svA * 8 + ch];
            uint4 pvB = hmv[(size_t)svB * 8 + ch];
            fma8(pvA, wA.x, wA.y, acc0, acc1);
            den0 += wA.x; den1 += wA.y;
            fma8(pvB, wB.x, wB.y, acc0, acc1);
            den0 += wB.x; den1 += wB.y;
        }
    }
    // reduce across the 8 edge-slots
#pragma unroll
    for (int m = 8; m < 64; m <<= 1) {
#pragma unroll
        for (int j = 0; j < 8; ++j) {
            acc0[j] += __shfl_xor(acc0[j], m);
            acc1[j] += __shfl_xor(acc1[j], m);
        }
        den0 += __shfl_xor(den0, m);
        den1 += __shfl_xor(den1, m);
    }
    if (slot == 0) {  // lanes 0..7 finalize (chunk = lane)
        float al0 = asn.x + adn.x + aes.x; al0 = al0 > 0.f ? al0 : 0.2f * al0;
        float al1 = asn.y + adn.y + aes.y; al1 = al1 > 0.f ? al1 : 0.2f * al1;
        float ws0 = __expf(al0), ws1 = __expf(al1);
        fma8(pvself, ws0, ws1, acc0, acc1);
        den0 += ws0; den1 += ws1;
        float inv0 = 1.f / (den0 + 1e-16f), inv1 = 1.f / (den1 + 1e-16f);
        float4* Sp = (float4*)(S + (size_t)n * 128);
        Sp[ch * 2]     = make_float4(acc0[0] * inv0, acc0[1] * inv0, acc0[2] * inv0, acc0[3] * inv0);
        Sp[ch * 2 + 1] = make_float4(acc0[4] * inv0, acc0[5] * inv0, acc0[6] * inv0, acc0[7] * inv0);
        Sp[16 + ch * 2]     = make_float4(acc1[0] * inv1, acc1[1] * inv1, acc1[2] * inv1, acc1[3] * inv1);
        Sp[16 + ch * 2 + 1] = make_float4(acc1[4] * inv1, acc1[5] * inv1, acc1[6] * inv1, acc1[7] * inv1);
    }
}

// ---------------- post-aggregation GEMM: h = relu(S @ Bmat + bias) ----------------
// LAST=0: epilogue fuses next-layer LN/affine -> hm_bf + attention dots.
// LAST=1: writes hbuf fp32.
template <int LAST>
__global__ __launch_bounds__(256) void post_gemm(
    const float* __restrict__ S, const unsigned short* __restrict__ gBhi,
    const unsigned short* __restrict__ gBlo, const float* __restrict__ bias,
    const float* __restrict__ ln_g, const float* __restrict__ ln_b,
    const float* __restrict__ mg, const float* __restrict__ mb,
    const float* __restrict__ vsn, const float* __restrict__ vdn,
    unsigned short* __restrict__ hm_bf, float* __restrict__ a_s, float* __restrict__ a_d,
    float* __restrict__ hbuf) {
    __shared__ unsigned short Ahi[64 * 128], Alo[64 * 128];
    __shared__ unsigned short Bhi[64 * 128], Blo[64 * 128];
    int tid = threadIdx.x;
    // B copy (pre-swizzled)
    {
        const uint4* sh = (const uint4*)gBhi;
        const uint4* sl = (const uint4*)gBlo;
        for (int i = tid; i < 1024; i += 256) {
            ((uint4*)Bhi)[i] = sh[i];
            ((uint4*)Blo)[i] = sl[i];
        }
    }
    // A staging: S rows fp32 -> bf16 hi/lo, chunk-swizzled. 8 lanes/node, 2 halves.
    {
        int i0 = tid >> 3, q = tid & 7;
#pragma unroll
        for (int half = 0; half < 2; ++half) {
            int i = half * 32 + i0;
            int node = blockIdx.x * 64 + i;
            const float4* rp = (const float4*)(S + (size_t)node * 128) + q * 4;
            float4 f0 = rp[0], f1 = rp[1], f2 = rp[2], f3 = rp[3];
            float f[16] = {f0.x, f0.y, f0.z, f0.w, f1.x, f1.y, f1.z, f1.w,
                           f2.x, f2.y, f2.z, f2.w, f3.x, f3.y, f3.z, f3.w};
            U16x8 hh[2], ll[2];
#pragma unroll
            for (int j = 0; j < 16; ++j) {
                unsigned short h16 = f2bf(f[j]);
                hh[j >> 3].u[j & 7] = h16;
                ll[j >> 3].u[j & 7] = f2bf(f[j] - bf2f(h16));
            }
#pragma unroll
            for (int c = 0; c < 2; ++c) {
                int cg = q * 2 + c;
                int off = i * 128 + ((cg ^ (i & 15)) << 3);
                *(short8*)(Ahi + off) = hh[c].v;
                *(short8*)(Alo + off) = ll[c].v;
            }
        }
    }
    __syncthreads();

    int w = tid >> 6, lane = tid & 63, col = lane & 15, quad = lane >> 4;
    int m = w * 16 + col;
    floatx4 acc[4] = {};
#pragma unroll
    for (int s = 0; s < 4; ++s) {
        int ca = (quad + 4 * s) ^ col;
        short8 ahi = *(const short8*)(Ahi + m * 128 + ca * 8);
        short8 alo = *(const short8*)(Alo + m * 128 + ca * 8);
#pragma unroll
        for (int t = 0; t < 4; ++t) {
            int off = (t * 16 + col) * 128 + ca * 8;
            short8 bhi = *(const short8*)(Bhi + off);
            short8 blo = *(const short8*)(Blo + off);
            acc[t] = __builtin_amdgcn_mfma_f32_16x16x32_bf16(alo, bhi, acc[t], 0, 0, 0);
            acc[t] = __builtin_amdgcn_mfma_f32_16x16x32_bf16(ahi, blo, acc[t], 0, 0, 0);
            acc[t] = __builtin_amdgcn_mfma_f32_16x16x32_bf16(ahi, bhi, acc[t], 0, 0, 0);
        }
    }
    int nodebase = blockIdx.x * 64 + w * 16;
    float bv[4];
#pragma unroll
    for (int t = 0; t < 4; ++t) bv[t] = bias[t * 16 + col];
    if (LAST) {
#pragma unroll
        for (int t = 0; t < 4; ++t)
#pragma unroll
            for (int r = 0; r < 4; ++r) {
                float hv = acc[t][r] + bv[t];
                hv = hv > 0.f ? hv : 0.f;
                hbuf[(size_t)(nodebase + quad * 4 + r) * 64 + t * 16 + col] = hv;
            }
    } else {
        float vsv[4], vsv1[4], vdv[4], vdv1[4], lg[4], lb[4], mgv[4], mbv[4];
#pragma unroll
        for (int t = 0; t < 4; ++t) {
            int c = t * 16 + col;
            vsv[t] = vsn[c]; vsv1[t] = vsn[64 + c];
            vdv[t] = vdn[c]; vdv1[t] = vdn[64 + c];
            lg[t] = ln_g[c]; lb[t] = ln_b[c];
            mgv[t] = mg[c]; mbv[t] = mb[c];
        }
#pragma unroll
        for (int r = 0; r < 4; ++r) {
            int node = nodebase + quad * 4 + r;
            float hv[4];
            float s = 0.f, sq = 0.f;
#pragma unroll
            for (int t = 0; t < 4; ++t) {
                float v = acc[t][r] + bv[t];
                v = v > 0.f ? v : 0.f;
                hv[t] = v;
                s += v; sq += v * v;
            }
            for (int off = 1; off < 16; off <<= 1) { s += __shfl_xor(s, off); sq += __shfl_xor(sq, off); }
            float mu = s * (1.f / 64.f);
            float var = sq * (1.f / 64.f) - mu * mu;
            float rs = rsqrtf(var + 1e-5f);
            float s0 = 0.f, s1 = 0.f, d0 = 0.f, d1 = 0.f;
#pragma unroll
            for (int t = 0; t < 4; ++t) {
                float hmv = mgv[t] * (lg[t] * (hv[t] - mu) * rs + lb[t]) + mbv[t];
                hm_bf[(size_t)node * 64 + t * 16 + col] = f2bf(hmv);
                s0 += hmv * vsv[t]; s1 += hmv * vsv1[t];
                d0 += hmv * vdv[t]; d1 += hmv * vdv1[t];
            }
            for (int off = 1; off < 16; off <<= 1) {
                s0 += __shfl_xor(s0, off); s1 += __shfl_xor(s1, off);
                d0 += __shfl_xor(d0, off); d1 += __shfl_xor(d1, off);
            }
            if (col == 0) {
                a_s[node * 2] = s0; a_s[node * 2 + 1] = s1;
                a_d[node * 2] = d0; a_d[node * 2 + 1] = d1;
            }
        }
    }
}

// ---------------- uv GEMM for the edge head (unchanged structure) ----------------
__global__ __launch_bounds__(256) void uv_gemm(
    const float* __restrict__ in, const unsigned short* __restrict__ gBhi,
    const unsigned short* __restrict__ gBlo, unsigned short* __restrict__ uv) {
    __shared__ unsigned short Ahi[64 * 64], Alo[64 * 64];
    __shared__ unsigned short Bhi[128 * 64], Blo[128 * 64];
    int tid = threadIdx.x;
    {
        const uint4* sh = (const uint4*)gBhi;
        const uint4* sl = (const uint4*)gBlo;
        for (int i = tid; i < 1024; i += 256) {
            ((uint4*)Bhi)[i] = sh[i];
            ((uint4*)Blo)[i] = sl[i];
        }
    }
    {
        int i = tid >> 2, q = tid & 3;
        int node = blockIdx.x * 64 + i;
        const float4* rp = (const float4*)(in + (size_t)node * 64);
        float4 va = rp[q * 4 + 0], vb = rp[q * 4 + 1], vc = rp[q * 4 + 2], vd = rp[q * 4 + 3];
        float f[16] = {va.x, va.y, va.z, va.w, vb.x, vb.y, vb.z, vb.w,
                       vc.x, vc.y, vc.z, vc.w, vd.x, vd.y, vd.z, vd.w};
        U16x8 hh[2], ll[2];
#pragma unroll
        for (int j = 0; j < 16; ++j) {
            unsigned short h16 = f2bf(f[j]);
            hh[j >> 3].u[j & 7] = h16;
            ll[j >> 3].u[j & 7] = f2bf(f[j] - bf2f(h16));
        }
#pragma unroll
        for (int c = 0; c < 2; ++c) {
            int cg = 2 * q + c;
            int off = i * 64 + ((cg ^ (i & 7)) << 3);
            *(short8*)(Ahi + off) = hh[c].v;
            *(short8*)(Alo + off) = ll[c].v;
        }
    }
    __syncthreads();
    int w = tid >> 6, lane = tid & 63, col = lane & 15, quad = lane >> 4;
    int m = w * 16 + col;
    floatx4 acc[8] = {};
#pragma unroll
    for (int s = 0; s < 2; ++s) {
        int ca = (quad + 4 * s) ^ (col & 7);
        short8 ahi = *(const short8*)(Ahi + m * 64 + ca * 8);
        short8 alo = *(const short8*)(Alo + m * 64 + ca * 8);
#pragma unroll
        for (int t = 0; t < 8; ++t) {
            int off = (t * 16 + col) * 64 + ca * 8;
            short8 bhi = *(const short8*)(Bhi + off);
            short8 blo = *(const short8*)(Blo + off);
            acc[t] = __builtin_amdgcn_mfma_f32_16x16x32_bf16(alo, bhi, acc[t], 0, 0, 0);
            acc[t] = __builtin_amdgcn_mfma_f32_16x16x32_bf16(ahi, blo, acc[t], 0, 0, 0);
            acc[t] = __builtin_amdgcn_mfma_f32_16x16x32_bf16(ahi, bhi, acc[t], 0, 0, 0);
        }
    }
    int nodebase = blockIdx.x * 64 + w * 16;
#pragma unroll
    for (int t = 0; t < 8; ++t)
#pragma unroll
        for (int r = 0; r < 4; ++r)
            uv[(size_t)(nodebase + quad * 4 + r) * 128 + t * 16 + col] = f2bf(acc[t][r]);
}

// ---------------- edge output head ----------------

__global__ void w1c_split_kernel(const float* __restrict__ W1,
                                 unsigned short* __restrict__ w1chi,
                                 unsigned short* __restrict__ w1clo) {
    int tid = threadIdx.x;
    int n = tid & 63, kc = tid >> 6;
#pragma unroll
    for (int j = 0; j < 8; ++j) {
        int k = kc * 8 + j;
        float wv = W1[(128 + k) * 64 + n];
        unsigned short h16 = f2bf(wv);
        w1chi[n * 32 + k] = h16;
        w1clo[n * 32 + k] = f2bf(wv - bf2f(h16));
    }
}

__global__ __launch_bounds__(256) void head2_kernel(
    const unsigned short* __restrict__ uv, const int* __restrict__ src,
    const int* __restrict__ dst, const float* __restrict__ edge_attr,
    const unsigned short* __restrict__ w1chi, const unsigned short* __restrict__ w1clo,
    const float* __restrict__ b1, const float* __restrict__ W2,
    const float* __restrict__ b2, float* __restrict__ out) {
    __shared__ float g[64][68];
    __shared__ unsigned short Abf[64 * 40];
    __shared__ unsigned short Bh[64 * 40], Bl[64 * 40];
    __shared__ int sA[64], dA[64];
    int tid = threadIdx.x;
    int base = blockIdx.x * 64;
    if (tid < 64) sA[tid] = src[base + tid];
    else if (tid < 128) dA[tid - 64] = dst[base + tid - 64];
    {
        int n = tid >> 2, c = tid & 3;
        *(short8*)(Bh + n * 40 + c * 8) = *(const short8*)(w1chi + n * 32 + c * 8);
        *(short8*)(Bl + n * 40 + c * 8) = *(const short8*)(w1clo + n * 32 + c * 8);
    }
    {
        int e = tid >> 2, q = tid & 3;
        const float4* p = (const float4*)(edge_attr + (size_t)(base + e) * 32 + q * 8);
        float4 f0 = p[0], f1 = p[1];
        U16x8 u;
        u.u[0] = f2bf(f0.x); u.u[1] = f2bf(f0.y); u.u[2] = f2bf(f0.z); u.u[3] = f2bf(f0.w);
        u.u[4] = f2bf(f1.x); u.u[5] = f2bf(f1.y); u.u[6] = f2bf(f1.z); u.u[7] = f2bf(f1.w);
        *(short8*)(Abf + e * 40 + q * 8) = u.v;
    }
    __syncthreads();
    {
        int e = tid >> 2, q = tid & 3;
        const uint4* su = (const uint4*)(uv + (size_t)sA[e] * 128);
        const uint4* dv = (const uint4*)(uv + (size_t)dA[e] * 128);
        uint4 U0 = su[2 * q], U1 = su[2 * q + 1];
        uint4 V0 = dv[8 + 2 * q], V1 = dv[9 + 2 * q];
        const float4* b1p = (const float4*)(b1 + q * 16);
        float bb[16];
#pragma unroll
        for (int j = 0; j < 4; ++j) {
            float4 b4 = b1p[j];
            bb[4 * j] = b4.x; bb[4 * j + 1] = b4.y; bb[4 * j + 2] = b4.z; bb[4 * j + 3] = b4.w;
        }
        unsigned int uw[8] = {U0.x, U0.y, U0.z, U0.w, U1.x, U1.y, U1.z, U1.w};
        unsigned int vw[8] = {V0.x, V0.y, V0.z, V0.w, V1.x, V1.y, V1.z, V1.w};
        float* gr = &g[e][q * 16];
#pragma unroll
        for (int j = 0; j < 8; ++j) {
            gr[2 * j] = bf2f((unsigned short)(uw[j] & 0xffff)) +
                        bf2f((unsigned short)(vw[j] & 0xffff)) + bb[2 * j];
            gr[2 * j + 1] = bf2f((unsigned short)(uw[j] >> 16)) +
                            bf2f((unsigned short)(vw[j] >> 16)) + bb[2 * j + 1];
        }
    }
    __syncthreads();

    int lane = tid & 63, w = tid >> 6, col = lane & 15, quad = lane >> 4;
    short8 a = *(const short8*)(Abf + (w * 16 + col) * 40 + quad * 8);
    floatx4 acc[4] = {};
#pragma unroll
    for (int t = 0; t < 4; ++t) {
        int off = (t * 16 + col) * 40 + quad * 8;
        short8 bh = *(const short8*)(Bh + off);
        short8 bl = *(const short8*)(Bl + off);
        acc[t] = __builtin_amdgcn_mfma_f32_16x16x32_bf16(a, bl, acc[t], 0, 0, 0);
        acc[t] = __builtin_amdgcn_mfma_f32_16x16x32_bf16(a, bh, acc[t], 0, 0, 0);
    }
    float sv[4] = {0.f, 0.f, 0.f, 0.f};
#pragma unroll
    for (int t = 0; t < 4; ++t) {
        float w2v = W2[t * 16 + col];
#pragma unroll
        for (int r = 0; r < 4; ++r) {
            float hid = acc[t][r] + g[w * 16 + quad * 4 + r][t * 16 + col];
            hid = hid > 0.f ? hid : 0.f;
            sv[r] += hid * w2v;
        }
    }
    float b2v = b2[0];
#pragma unroll
    for (int r = 0; r < 4; ++r) {
        float v = sv[r];
        v += __shfl_xor(v, 1);
        v += __shfl_xor(v, 2);
        v += __shfl_xor(v, 4);
        v += __shfl_xor(v, 8);
        if (col == 0) out[base + w * 16 + quad * 4 + r] = v + b2v;
    }
}

// ---------------- launch ----------------

extern "C" void kernel_launch(void* const* d_in, const int* in_sizes, int n_in,
                              void* d_out, int out_size, void* d_ws, size_t ws_size,
                              hipStream_t stream) {
    const float* x            = (const float*)d_in[0];
    const int*   edge_index   = (const int*)d_in[1];
    const float* edge_attr    = (const float*)d_in[2];
    const float* manual_gamma = (const float*)d_in[3];
    const float* manual_beta  = (const float*)d_in[4];
    const float* embed_W      = (const float*)d_in[5];
    const float* embed_b      = (const float*)d_in[6];
    const float* ln_gamma     = (const float*)d_in[7];
    const float* ln_beta      = (const float*)d_in[8];
    const float* lin_W        = (const float*)d_in[9];
    const float* lin_edge_W   = (const float*)d_in[10];
    const float* att_src      = (const float*)d_in[11];
    const float* att_dst      = (const float*)d_in[12];
    const float* att_edge     = (const float*)d_in[13];
    const float* gat_bias     = (const float*)d_in[14];
    const float* head_W1      = (const float*)d_in[15];
    const float* head_b1      = (const float*)d_in[16];
    const float* head_W2      = (const float*)d_in[17];
    const float* head_b2      = (const float*)d_in[18];
    float* out = (float*)d_out;

    const int* src = edge_index;
    const int* dst = edge_index + EE;

    char* ws = (char*)d_ws;
    size_t off = 0;
    auto alloc = [&](size_t bytes) {
        void* p = ws + off;
        off += (bytes + 255) & ~(size_t)255;
        return p;
    };
    int*   deg        = (int*)alloc(NN * 4);
    int*   row_ptr    = (int*)alloc((NN + 1) * 4);
    int*   cnt        = (int*)alloc(NN * 4);
    int2*  sedge      = (int2*)alloc((size_t)EE * 8);
    float* a_e_sorted = (float*)alloc((size_t)LL * EE * 2 * 4);
    float* a_e_self   = (float*)alloc((size_t)LL * NN * 2 * 4);
    float* vbuf       = (float*)alloc(LL * 64 * 4);
    float* vs         = (float*)alloc(LL * 128 * 4);
    float* vvd        = (float*)alloc(LL * 128 * 4);
    float* hbuf       = (float*)alloc((size_t)NN * 64 * 4);
    float* a_s        = (float*)alloc((size_t)NN * 2 * 4);
    float* a_d        = (float*)alloc((size_t)NN * 2 * 4);
    float* Sbuf       = (float*)alloc((size_t)NN * 128 * 4);
    unsigned short* hm_bf = (unsigned short*)alloc((size_t)NN * 64 * 2);
    unsigned short* uvbuf = (unsigned short*)alloc((size_t)NN * 128 * 2);
    unsigned short* gBhi  = (unsigned short*)alloc((size_t)7 * 128 * 64 * 2);
    unsigned short* gBlo  = (unsigned short*)alloc((size_t)7 * 128 * 64 * 2);
    unsigned short* w1chi = (unsigned short*)alloc(64 * 32 * 2);
    unsigned short* w1clo = (unsigned short*)alloc(64 * 32 * 2);
    if (off > ws_size) return;  // insufficient workspace — fail visibly

    hipMemsetAsync(deg, 0, NN * 4, stream);
    hipMemsetAsync(cnt, 0, NN * 4, stream);

    deg_kernel<<<EE / 256, 256, 0, stream>>>(dst, deg);
    scan_kernel<<<1, 1024, 0, stream>>>(deg, row_ptr);
    fill_kernel<<<EE / 256, 256, 0, stream>>>(src, dst, row_ptr, cnt, sedge);
    vmake_kernel<<<1, 384, 0, stream>>>(lin_edge_W, att_edge, vbuf);
    ae_kernel<<<(EE + 127) / 128, 128, 0, stream>>>(edge_attr, sedge, vbuf, a_e_sorted);
    aeself_kernel<<<NN / 4, 256, 0, stream>>>(a_e_sorted, row_ptr, a_e_self);
    vsmake_kernel<<<LL, 256, 0, stream>>>(lin_W, att_src, att_dst, vs, vvd);
    wprep_kernel<<<7, 256, 0, stream>>>(lin_W, head_W1, gBhi, gBlo);
    w1c_split_kernel<<<1, 256, 0, stream>>>(head_W1, w1chi, w1clo);
    embed_ln_kernel<<<NN / 4, 256, 0, stream>>>(x, embed_W, embed_b, ln_gamma, ln_beta,
                                                manual_gamma, manual_beta, vs, vvd,
                                                hm_bf, a_s, a_d);

    for (int l = 0; l < LL; ++l) {
        aggregate4_kernel<<<NN / 4, 256, 0, stream>>>(
            hm_bf, a_s, a_d, a_e_sorted + (size_t)l * EE * 2,
            a_e_self + (size_t)l * NN * 2, row_ptr, sedge, Sbuf);
        if (l < LL - 1) {
            post_gemm<0><<<NN / 64, 256, 0, stream>>>(
                Sbuf, gBhi + (size_t)l * 128 * 64, gBlo + (size_t)l * 128 * 64,
                gat_bias + l * 64, ln_gamma + (l + 1) * 64, ln_beta + (l + 1) * 64,
                manual_gamma + (l + 1) * 64, manual_beta + (l + 1) * 64,
                vs + (l + 1) * 128, vvd + (l + 1) * 128, hm_bf, a_s, a_d, nullptr);
        } else {
            post_gemm<1><<<NN / 64, 256, 0, stream>>>(
                Sbuf, gBhi + (size_t)l * 128 * 64, gBlo + (size_t)l * 128 * 64,
                gat_bias + l * 64, nullptr, nullptr, nullptr, nullptr,
                nullptr, nullptr, nullptr, nullptr, nullptr, hbuf);
        }
    }

    uv_gemm<<<NN / 64, 256, 0, stream>>>(hbuf, gBhi + (size_t)6 * 128 * 64,
                                         gBlo + (size_t)6 * 128 * 64, uvbuf);
    head2_kernel<<<EE / 64, 256, 0, stream>>>(uvbuf, src, dst, edge_attr, w1chi, w1clo,
                                              head_b1, head_W2, head_b2, out);
}

// Round 7
// 519.986 us; speedup vs baseline: 1.0700x; 1.0700x over previous
//
#include <hip/hip_runtime.h>
#include <hip/hip_bf16.h>
#include <math.h>

#define NN 32768
#define EE 524288
#define LL 6

typedef __attribute__((ext_vector_type(8))) short short8;
typedef __attribute__((ext_vector_type(4))) float floatx4;

union U16x8 { short8 v; unsigned short u[8]; };

__device__ __forceinline__ unsigned short f2bf(float x) {
    union { float f; unsigned int u; } v; v.f = x;
    unsigned int r = v.u + 0x7fffu + ((v.u >> 16) & 1u);
    return (unsigned short)(r >> 16);
}
__device__ __forceinline__ float bf2f(unsigned short h) {
    union { unsigned int u; float f; } v; v.u = (unsigned int)h << 16;
    return v.f;
}

// ---------------- preprocessing ----------------

__global__ void deg_kernel(const int* __restrict__ dst, int* __restrict__ deg) {
    int e = blockIdx.x * 256 + threadIdx.x;
    if (e < EE) atomicAdd(&deg[dst[e]], 1);
}

__global__ __launch_bounds__(1024) void scan_kernel(const int* __restrict__ deg,
                                                    int* __restrict__ row_ptr) {
    __shared__ int bs[1024];
    int t = threadIdx.x;
    int base = t * 32;
    int loc[32];
    int s = 0;
#pragma unroll
    for (int i = 0; i < 32; ++i) { int v = deg[base + i]; loc[i] = s; s += v; }
    bs[t] = s;
    __syncthreads();
    for (int off = 1; off < 1024; off <<= 1) {
        int v = (t >= off) ? bs[t - off] : 0;
        __syncthreads();
        bs[t] += v;
        __syncthreads();
    }
    int pre = (t == 0) ? 0 : bs[t - 1];
#pragma unroll
    for (int i = 0; i < 32; ++i) row_ptr[base + i] = pre + loc[i];
    if (t == 1023) row_ptr[NN] = bs[1023];
}

__global__ void fill_kernel(const int* __restrict__ src, const int* __restrict__ dst,
                            const int* __restrict__ row_ptr, int* __restrict__ cnt,
                            int2* __restrict__ sedge) {
    int e = blockIdx.x * 256 + threadIdx.x;
    if (e >= EE) return;
    int d = dst[e];
    int pos = row_ptr[d] + atomicAdd(&cnt[d], 1);
    sedge[pos] = make_int2(src[e], e);
}

// v[l][ed][h] = sum_c lin_edge_W[l][ed][h*64+c] * att_edge[l][h][c]
__global__ void vmake_kernel(const float* __restrict__ lin_edge_W,
                             const float* __restrict__ att_edge,
                             float* __restrict__ v) {
    int t = threadIdx.x;
    if (t >= 384) return;
    int l = t >> 6; int r = t & 63; int ed = r >> 1; int hh = r & 1;
    const float* w = lin_edge_W + l * 32 * 128 + ed * 128 + hh * 64;
    const float* a = att_edge + l * 128 + hh * 64;
    float s = 0.f;
#pragma unroll 8
    for (int c = 0; c < 64; ++c) s += w[c] * a[c];
    v[t] = s;
}

// vs[l][h*64+k] = sum_c lin_W[l][k][h*64+c]*att_src[l][h][c]; vvd same with att_dst
__global__ void vsmake_kernel(const float* __restrict__ lin_W,
                              const float* __restrict__ att_src,
                              const float* __restrict__ att_dst,
                              float* __restrict__ vs, float* __restrict__ vvd) {
    int l = blockIdx.x;
    int tid = threadIdx.x;
    int sel = tid >> 7, idx = tid & 127;
    int h = idx >> 6, k = idx & 63;
    const float* att = (sel ? att_dst : att_src) + l * 128 + h * 64;
    const float* wr = lin_W + ((size_t)l * 64 + k) * 128 + h * 64;
    float s = 0.f;
#pragma unroll 8
    for (int c = 0; c < 64; ++c) s += wr[c] * att[c];
    (sel ? vvd : vs)[l * 128 + idx] = s;
}

// a_e in ORIGINAL edge order (coalesced edge_attr stream), all layers
__global__ void ae_kernel(const float* __restrict__ edge_attr,
                          const float* __restrict__ v,
                          float* __restrict__ aeo) {
    __shared__ float sv[384];
    int tid = threadIdx.x;
    for (int i = tid; i < 384; i += 128) sv[i] = v[i];
    __syncthreads();
    int e = blockIdx.x * 128 + tid;
    if (e >= EE) return;
    float ea[32];
    const float4* p = (const float4*)(edge_attr + (size_t)e * 32);
#pragma unroll
    for (int i = 0; i < 8; ++i) {
        float4 f = p[i];
        ea[4 * i] = f.x; ea[4 * i + 1] = f.y; ea[4 * i + 2] = f.z; ea[4 * i + 3] = f.w;
    }
#pragma unroll
    for (int l = 0; l < LL; ++l) {
        float s0 = 0.f, s1 = 0.f;
#pragma unroll
        for (int ed = 0; ed < 32; ++ed) {
            float x = ea[ed];
            s0 += x * sv[l * 64 + ed * 2];
            s1 += x * sv[l * 64 + ed * 2 + 1];
        }
        aeo[((size_t)l * EE + e) * 2] = s0;
        aeo[((size_t)l * EE + e) * 2 + 1] = s1;
    }
}

// embed + layer-0 LN/affine + layer-0 attention dots. 4 nodes/block, 1 wave/node.
__global__ __launch_bounds__(256) void embed_ln_kernel(
    const float* __restrict__ x, const float* __restrict__ W, const float* __restrict__ b,
    const float* __restrict__ ln_g, const float* __restrict__ ln_b,
    const float* __restrict__ mg, const float* __restrict__ mb,
    const float* __restrict__ vs0, const float* __restrict__ vd0,
    unsigned short* __restrict__ hm_bf, float* __restrict__ a_s, float* __restrict__ a_d) {
    __shared__ float xr[4][64];
    int w = threadIdx.x >> 6, j = threadIdx.x & 63;
    int n = blockIdx.x * 4 + w;
    xr[w][j] = x[(size_t)n * 64 + j];
    __syncthreads();
    float acc = b[j];
#pragma unroll 8
    for (int k = 0; k < 64; ++k) acc += xr[w][k] * W[k * 64 + j];
    float s = acc, sq = acc * acc;
    for (int off = 1; off < 64; off <<= 1) { s += __shfl_xor(s, off); sq += __shfl_xor(sq, off); }
    float mu = s * (1.f / 64.f);
    float var = sq * (1.f / 64.f) - mu * mu;
    float rs = rsqrtf(var + 1e-5f);
    float hm = mg[j] * (ln_g[j] * (acc - mu) * rs + ln_b[j]) + mb[j];
    hm_bf[(size_t)n * 64 + j] = f2bf(hm);
    float s0 = hm * vs0[j], s1 = hm * vs0[64 + j];
    float d0 = hm * vd0[j], d1 = hm * vd0[64 + j];
    for (int off = 1; off < 64; off <<= 1) {
        s0 += __shfl_xor(s0, off); s1 += __shfl_xor(s1, off);
        d0 += __shfl_xor(d0, off); d1 += __shfl_xor(d1, off);
    }
    if (j == 0) {
        a_s[n * 2] = s0; a_s[n * 2 + 1] = s1;
        a_d[n * 2] = d0; a_d[n * 2 + 1] = d1;
    }
}

// Pre-swizzled bf16 hi/lo B tiles (blocks 0..5 = 0.5*lin_W head-stacked; block 6 = uv)
__global__ __launch_bounds__(256) void wprep_kernel(const float* __restrict__ lin_W,
                                                    const float* __restrict__ head_W1,
                                                    unsigned short* __restrict__ gBhi,
                                                    unsigned short* __restrict__ gBlo) {
    int bb = blockIdx.x;
    int tid = threadIdx.x;
    unsigned short* dh = gBhi + (size_t)bb * 128 * 64;
    unsigned short* dl = gBlo + (size_t)bb * 128 * 64;
    if (bb < 6) {
        int n2 = tid & 63, kh = tid >> 6;
        U16x8 hh[4], ll[4];
        for (int kk = 0; kk < 32; ++kk) {
            int j = kh * 32 + kk;
            int h = j >> 6, k = j & 63;
            float wv = 0.5f * lin_W[((size_t)bb * 64 + k) * 128 + h * 64 + n2];
            unsigned short h16 = f2bf(wv);
            hh[kk >> 3].u[kk & 7] = h16;
            ll[kk >> 3].u[kk & 7] = f2bf(wv - bf2f(h16));
        }
#pragma unroll
        for (int c = 0; c < 4; ++c) {
            int cg = kh * 4 + c;
            int off = n2 * 128 + ((cg ^ (n2 & 15)) << 3);
            *(short8*)(dh + off) = hh[c].v;
            *(short8*)(dl + off) = ll[c].v;
        }
    } else {
        int n = tid & 127, kh = tid >> 7;
        U16x8 hh[4], ll[4];
        for (int kk = 0; kk < 32; ++kk) {
            int k = kh * 32 + kk;
            float wv = (n < 64) ? head_W1[k * 64 + n] : head_W1[(64 + k) * 64 + (n - 64)];
            unsigned short h16 = f2bf(wv);
            hh[kk >> 3].u[kk & 7] = h16;
            ll[kk >> 3].u[kk & 7] = f2bf(wv - bf2f(h16));
        }
#pragma unroll
        for (int c = 0; c < 4; ++c) {
            int cg = kh * 4 + c;
            int off = n * 64 + ((cg ^ (n & 7)) << 3);
            *(short8*)(dh + off) = hh[c].v;
            *(short8*)(dl + off) = ll[c].v;
        }
    }
}

// ---------------- GAT aggregation v5 ----------------
// - ae gathered from edge-order table via sedge.y
// - self-loop a_e computed inline (mean of gathered ae)
// - emits the MFMA A-tile (bf16, pre-swizzled) directly
__device__ __forceinline__ void fma8(uint4 pv, float w0, float w1, float* a0, float* a1) {
    unsigned int u[4] = {pv.x, pv.y, pv.z, pv.w};
#pragma unroll
    for (int j = 0; j < 4; ++j) {
        union { unsigned int q; float f; } lo, hi;
        lo.q = u[j] << 16; hi.q = u[j] & 0xffff0000u;
        a0[2 * j] += w0 * lo.f;  a1[2 * j] += w1 * lo.f;
        a0[2 * j + 1] += w0 * hi.f;  a1[2 * j + 1] += w1 * hi.f;
    }
}

__global__ __launch_bounds__(256) void aggregate5_kernel(
    const unsigned short* __restrict__ hm_bf, const float* __restrict__ a_s,
    const float* __restrict__ a_d, const float* __restrict__ aeo,
    const int* __restrict__ row_ptr, const int2* __restrict__ sedge,
    unsigned short* __restrict__ Abf) {
    __shared__ float2 swg[4][64];
    __shared__ int ssv[4][64];
    int w = threadIdx.x >> 6, lane = threadIdx.x & 63;
    int n = blockIdx.x * 4 + w;
    int slot = lane >> 3, ch = lane & 7;
    const float2* as2 = (const float2*)a_s;
    const float2* ae2 = (const float2*)aeo;
    const uint4* hmv = (const uint4*)hm_bf;
    float2 adn = ((const float2*)a_d)[n];
    float2 asn = as2[n];
    uint4 pvself = hmv[(size_t)n * 8 + ch];
    int beg = row_ptr[n], end = row_ptr[n + 1];

    float acc0[8] = {}, acc1[8] = {};
    float den0 = 0.f, den1 = 0.f, aex = 0.f, aey = 0.f;

    for (int cs = beg; cs < end; cs += 64) {
        int cnt = min(64, end - cs);
        float2 wpair = make_float2(0.f, 0.f);
        int sval = n;
        if (lane < cnt) {
            int2 se = sedge[cs + lane];
            float2 ae = ae2[se.y];
            float2 as = as2[se.x];
            aex += ae.x; aey += ae.y;
            float al0 = as.x + adn.x + ae.x; al0 = al0 > 0.f ? al0 : 0.2f * al0;
            float al1 = as.y + adn.y + ae.y; al1 = al1 > 0.f ? al1 : 0.2f * al1;
            wpair = make_float2(__expf(al0), __expf(al1));
            sval = se.x;
        }
        swg[w][lane] = wpair;
        ssv[w][lane] = sval;
        // per-wave LDS produce->consume; in-order within the wave, waitcnt-protected
        int ng2 = (cnt + 15) >> 4;
        for (int g2 = 0; g2 < ng2; ++g2) {
            int eA = g2 * 16 + slot, eB = g2 * 16 + 8 + slot;
            float2 wA = swg[w][eA];
            float2 wB = swg[w][eB];
            int svA = ssv[w][eA];
            int svB = ssv[w][eB];
            uint4 pvA = hmv[(size_t)svA * 8 + ch];
            uint4 pvB = hmv[(size_t)svB * 8 + ch];
            fma8(pvA, wA.x, wA.y, acc0, acc1);
            den0 += wA.x; den1 += wA.y;
            fma8(pvB, wB.x, wB.y, acc0, acc1);
            den0 += wB.x; den1 += wB.y;
        }
    }
#pragma unroll
    for (int m = 8; m < 64; m <<= 1) {
#pragma unroll
        for (int j = 0; j < 8; ++j) {
            acc0[j] += __shfl_xor(acc0[j], m);
            acc1[j] += __shfl_xor(acc1[j], m);
        }
        den0 += __shfl_xor(den0, m);
        den1 += __shfl_xor(den1, m);
        aex += __shfl_xor(aex, m);
        aey += __shfl_xor(aey, m);
    }
    if (slot == 0) {
        float invd = 1.f / fmaxf((float)(end - beg), 1.f);
        float al0 = asn.x + adn.x + aex * invd; al0 = al0 > 0.f ? al0 : 0.2f * al0;
        float al1 = asn.y + adn.y + aey * invd; al1 = al1 > 0.f ? al1 : 0.2f * al1;
        float ws0 = __expf(al0), ws1 = __expf(al1);
        fma8(pvself, ws0, ws1, acc0, acc1);
        den0 += ws0; den1 += ws1;
        float inv0 = 1.f / (den0 + 1e-16f), inv1 = 1.f / (den1 + 1e-16f);
        U16x8 h0, h1;
#pragma unroll
        for (int j = 0; j < 8; ++j) {
            h0.u[j] = f2bf(acc0[j] * inv0);
            h1.u[j] = f2bf(acc1[j] * inv1);
        }
        int i15 = n & 15;
        unsigned short* row = Abf + (size_t)n * 128;
        *(short8*)(row + ((ch ^ i15) << 3)) = h0.v;
        *(short8*)(row + (((8 + ch) ^ i15) << 3)) = h1.v;
    }
}

// ---------------- post-aggregation GEMM: h = relu(A @ Bmat + bias) ----------------
// A is bf16 pre-swizzled (from aggregate5). LAST=0 fuses next-layer LN + att dots.
template <int LAST>
__global__ __launch_bounds__(256) void post_gemm(
    const unsigned short* __restrict__ Abf, const unsigned short* __restrict__ gBhi,
    const unsigned short* __restrict__ gBlo, const float* __restrict__ bias,
    const float* __restrict__ ln_g, const float* __restrict__ ln_b,
    const float* __restrict__ mg, const float* __restrict__ mb,
    const float* __restrict__ vsn, const float* __restrict__ vdn,
    unsigned short* __restrict__ hm_bf, float* __restrict__ a_s, float* __restrict__ a_d,
    float* __restrict__ hbuf) {
    __shared__ unsigned short Ahi[64 * 128];
    __shared__ unsigned short Bhi[64 * 128], Blo[64 * 128];
    int tid = threadIdx.x;
    {
        const uint4* sa = (const uint4*)(Abf + (size_t)blockIdx.x * 64 * 128);
        const uint4* sh = (const uint4*)gBhi;
        const uint4* sl = (const uint4*)gBlo;
        for (int i = tid; i < 1024; i += 256) {
            ((uint4*)Ahi)[i] = sa[i];
            ((uint4*)Bhi)[i] = sh[i];
            ((uint4*)Blo)[i] = sl[i];
        }
    }
    __syncthreads();

    int w = tid >> 6, lane = tid & 63, col = lane & 15, quad = lane >> 4;
    int m = w * 16 + col;
    floatx4 acc[4] = {};
#pragma unroll
    for (int s = 0; s < 4; ++s) {
        int ca = (quad + 4 * s) ^ col;
        short8 ahi = *(const short8*)(Ahi + m * 128 + ca * 8);
#pragma unroll
        for (int t = 0; t < 4; ++t) {
            int off = (t * 16 + col) * 128 + ca * 8;
            short8 bhi = *(const short8*)(Bhi + off);
            short8 blo = *(const short8*)(Blo + off);
            acc[t] = __builtin_amdgcn_mfma_f32_16x16x32_bf16(ahi, blo, acc[t], 0, 0, 0);
            acc[t] = __builtin_amdgcn_mfma_f32_16x16x32_bf16(ahi, bhi, acc[t], 0, 0, 0);
        }
    }
    int nodebase = blockIdx.x * 64 + w * 16;
    float bv[4];
#pragma unroll
    for (int t = 0; t < 4; ++t) bv[t] = bias[t * 16 + col];
    if (LAST) {
#pragma unroll
        for (int t = 0; t < 4; ++t)
#pragma unroll
            for (int r = 0; r < 4; ++r) {
                float hv = acc[t][r] + bv[t];
                hv = hv > 0.f ? hv : 0.f;
                hbuf[(size_t)(nodebase + quad * 4 + r) * 64 + t * 16 + col] = hv;
            }
    } else {
        float vsv[4], vsv1[4], vdv[4], vdv1[4], lg[4], lb[4], mgv[4], mbv[4];
#pragma unroll
        for (int t = 0; t < 4; ++t) {
            int c = t * 16 + col;
            vsv[t] = vsn[c]; vsv1[t] = vsn[64 + c];
            vdv[t] = vdn[c]; vdv1[t] = vdn[64 + c];
            lg[t] = ln_g[c]; lb[t] = ln_b[c];
            mgv[t] = mg[c]; mbv[t] = mb[c];
        }
#pragma unroll
        for (int r = 0; r < 4; ++r) {
            int node = nodebase + quad * 4 + r;
            float hv[4];
            float s = 0.f, sq = 0.f;
#pragma unroll
            for (int t = 0; t < 4; ++t) {
                float v = acc[t][r] + bv[t];
                v = v > 0.f ? v : 0.f;
                hv[t] = v;
                s += v; sq += v * v;
            }
            for (int off = 1; off < 16; off <<= 1) { s += __shfl_xor(s, off); sq += __shfl_xor(sq, off); }
            float mu = s * (1.f / 64.f);
            float var = sq * (1.f / 64.f) - mu * mu;
            float rs = rsqrtf(var + 1e-5f);
            float s0 = 0.f, s1 = 0.f, d0 = 0.f, d1 = 0.f;
#pragma unroll
            for (int t = 0; t < 4; ++t) {
                float hmv = mgv[t] * (lg[t] * (hv[t] - mu) * rs + lb[t]) + mbv[t];
                hm_bf[(size_t)node * 64 + t * 16 + col] = f2bf(hmv);
                s0 += hmv * vsv[t]; s1 += hmv * vsv1[t];
                d0 += hmv * vdv[t]; d1 += hmv * vdv1[t];
            }
            for (int off = 1; off < 16; off <<= 1) {
                s0 += __shfl_xor(s0, off); s1 += __shfl_xor(s1, off);
                d0 += __shfl_xor(d0, off); d1 += __shfl_xor(d1, off);
            }
            if (col == 0) {
                a_s[node * 2] = s0; a_s[node * 2 + 1] = s1;
                a_d[node * 2] = d0; a_d[node * 2 + 1] = d1;
            }
        }
    }
}

// ---------------- uv GEMM for the edge head ----------------
__global__ __launch_bounds__(256) void uv_gemm(
    const float* __restrict__ in, const unsigned short* __restrict__ gBhi,
    const unsigned short* __restrict__ gBlo, unsigned short* __restrict__ uv) {
    __shared__ unsigned short Ahi[64 * 64], Alo[64 * 64];
    __shared__ unsigned short Bhi[128 * 64], Blo[128 * 64];
    int tid = threadIdx.x;
    {
        const uint4* sh = (const uint4*)gBhi;
        const uint4* sl = (const uint4*)gBlo;
        for (int i = tid; i < 1024; i += 256) {
            ((uint4*)Bhi)[i] = sh[i];
            ((uint4*)Blo)[i] = sl[i];
        }
    }
    {
        int i = tid >> 2, q = tid & 3;
        int node = blockIdx.x * 64 + i;
        const float4* rp = (const float4*)(in + (size_t)node * 64);
        float4 va = rp[q * 4 + 0], vb = rp[q * 4 + 1], vc = rp[q * 4 + 2], vd = rp[q * 4 + 3];
        float f[16] = {va.x, va.y, va.z, va.w, vb.x, vb.y, vb.z, vb.w,
                       vc.x, vc.y, vc.z, vc.w, vd.x, vd.y, vd.z, vd.w};
        U16x8 hh[2], ll[2];
#pragma unroll
        for (int j = 0; j < 16; ++j) {
            unsigned short h16 = f2bf(f[j]);
            hh[j >> 3].u[j & 7] = h16;
            ll[j >> 3].u[j & 7] = f2bf(f[j] - bf2f(h16));
        }
#pragma unroll
        for (int c = 0; c < 2; ++c) {
            int cg = 2 * q + c;
            int off = i * 64 + ((cg ^ (i & 7)) << 3);
            *(short8*)(Ahi + off) = hh[c].v;
            *(short8*)(Alo + off) = ll[c].v;
        }
    }
    __syncthreads();
    int w = tid >> 6, lane = tid & 63, col = lane & 15, quad = lane >> 4;
    int m = w * 16 + col;
    floatx4 acc[8] = {};
#pragma unroll
    for (int s = 0; s < 2; ++s) {
        int ca = (quad + 4 * s) ^ (col & 7);
        short8 ahi = *(const short8*)(Ahi + m * 64 + ca * 8);
        short8 alo = *(const short8*)(Alo + m * 64 + ca * 8);
#pragma unroll
        for (int t = 0; t < 8; ++t) {
            int off = (t * 16 + col) * 64 + ca * 8;
            short8 bhi = *(const short8*)(Bhi + off);
            short8 blo = *(const short8*)(Blo + off);
            acc[t] = __builtin_amdgcn_mfma_f32_16x16x32_bf16(alo, bhi, acc[t], 0, 0, 0);
            acc[t] = __builtin_amdgcn_mfma_f32_16x16x32_bf16(ahi, blo, acc[t], 0, 0, 0);
            acc[t] = __builtin_amdgcn_mfma_f32_16x16x32_bf16(ahi, bhi, acc[t], 0, 0, 0);
        }
    }
    int nodebase = blockIdx.x * 64 + w * 16;
#pragma unroll
    for (int t = 0; t < 8; ++t)
#pragma unroll
        for (int r = 0; r < 4; ++r)
            uv[(size_t)(nodebase + quad * 4 + r) * 128 + t * 16 + col] = f2bf(acc[t][r]);
}

// ---------------- edge output head ----------------

__global__ void w1c_split_kernel(const float* __restrict__ W1,
                                 unsigned short* __restrict__ w1chi,
                                 unsigned short* __restrict__ w1clo) {
    int tid = threadIdx.x;
    int n = tid & 63, kc = tid >> 6;
#pragma unroll
    for (int j = 0; j < 8; ++j) {
        int k = kc * 8 + j;
        float wv = W1[(128 + k) * 64 + n];
        unsigned short h16 = f2bf(wv);
        w1chi[n * 32 + k] = h16;
        w1clo[n * 32 + k] = f2bf(wv - bf2f(h16));
    }
}

__global__ __launch_bounds__(256) void head2_kernel(
    const unsigned short* __restrict__ uv, const int* __restrict__ src,
    const int* __restrict__ dst, const float* __restrict__ edge_attr,
    const unsigned short* __restrict__ w1chi, const unsigned short* __restrict__ w1clo,
    const float* __restrict__ b1, const float* __restrict__ W2,
    const float* __restrict__ b2, float* __restrict__ out) {
    __shared__ float g[64][68];
    __shared__ unsigned short Abf[64 * 40];
    __shared__ unsigned short Bh[64 * 40], Bl[64 * 40];
    __shared__ int sA[64], dA[64];
    int tid = threadIdx.x;
    int base = blockIdx.x * 64;
    if (tid < 64) sA[tid] = src[base + tid];
    else if (tid < 128) dA[tid - 64] = dst[base + tid - 64];
    {
        int n = tid >> 2, c = tid & 3;
        *(short8*)(Bh + n * 40 + c * 8) = *(const short8*)(w1chi + n * 32 + c * 8);
        *(short8*)(Bl + n * 40 + c * 8) = *(const short8*)(w1clo + n * 32 + c * 8);
    }
    {
        int e = tid >> 2, q = tid & 3;
        const float4* p = (const float4*)(edge_attr + (size_t)(base + e) * 32 + q * 8);
        float4 f0 = p[0], f1 = p[1];
        U16x8 u;
        u.u[0] = f2bf(f0.x); u.u[1] = f2bf(f0.y); u.u[2] = f2bf(f0.z); u.u[3] = f2bf(f0.w);
        u.u[4] = f2bf(f1.x); u.u[5] = f2bf(f1.y); u.u[6] = f2bf(f1.z); u.u[7] = f2bf(f1.w);
        *(short8*)(Abf + e * 40 + q * 8) = u.v;
    }
    __syncthreads();
    {
        int e = tid >> 2, q = tid & 3;
        const uint4* su = (const uint4*)(uv + (size_t)sA[e] * 128);
        const uint4* dv = (const uint4*)(uv + (size_t)dA[e] * 128);
        uint4 U0 = su[2 * q], U1 = su[2 * q + 1];
        uint4 V0 = dv[8 + 2 * q], V1 = dv[9 + 2 * q];
        const float4* b1p = (const float4*)(b1 + q * 16);
        float bb[16];
#pragma unroll
        for (int j = 0; j < 4; ++j) {
            float4 b4 = b1p[j];
            bb[4 * j] = b4.x; bb[4 * j + 1] = b4.y; bb[4 * j + 2] = b4.z; bb[4 * j + 3] = b4.w;
        }
        unsigned int uw[8] = {U0.x, U0.y, U0.z, U0.w, U1.x, U1.y, U1.z, U1.w};
        unsigned int vw[8] = {V0.x, V0.y, V0.z, V0.w, V1.x, V1.y, V1.z, V1.w};
        float* gr = &g[e][q * 16];
#pragma unroll
        for (int j = 0; j < 8; ++j) {
            gr[2 * j] = bf2f((unsigned short)(uw[j] & 0xffff)) +
                        bf2f((unsigned short)(vw[j] & 0xffff)) + bb[2 * j];
            gr[2 * j + 1] = bf2f((unsigned short)(uw[j] >> 16)) +
                            bf2f((unsigned short)(vw[j] >> 16)) + bb[2 * j + 1];
        }
    }
    __syncthreads();

    int lane = tid & 63, w = tid >> 6, col = lane & 15, quad = lane >> 4;
    short8 a = *(const short8*)(Abf + (w * 16 + col) * 40 + quad * 8);
    floatx4 acc[4] = {};
#pragma unroll
    for (int t = 0; t < 4; ++t) {
        int off = (t * 16 + col) * 40 + quad * 8;
        short8 bh = *(const short8*)(Bh + off);
        short8 bl = *(const short8*)(Bl + off);
        acc[t] = __builtin_amdgcn_mfma_f32_16x16x32_bf16(a, bl, acc[t], 0, 0, 0);
        acc[t] = __builtin_amdgcn_mfma_f32_16x16x32_bf16(a, bh, acc[t], 0, 0, 0);
    }
    float sv[4] = {0.f, 0.f, 0.f, 0.f};
#pragma unroll
    for (int t = 0; t < 4; ++t) {
        float w2v = W2[t * 16 + col];
#pragma unroll
        for (int r = 0; r < 4; ++r) {
            float hid = acc[t][r] + g[w * 16 + quad * 4 + r][t * 16 + col];
            hid = hid > 0.f ? hid : 0.f;
            sv[r] += hid * w2v;
        }
    }
    float b2v = b2[0];
#pragma unroll
    for (int r = 0; r < 4; ++r) {
        float v = sv[r];
        v += __shfl_xor(v, 1);
        v += __shfl_xor(v, 2);
        v += __shfl_xor(v, 4);
        v += __shfl_xor(v, 8);
        if (col == 0) out[base + w * 16 + quad * 4 + r] = v + b2v;
    }
}

// ---------------- launch ----------------

extern "C" void kernel_launch(void* const* d_in, const int* in_sizes, int n_in,
                              void* d_out, int out_size, void* d_ws, size_t ws_size,
                              hipStream_t stream) {
    const float* x            = (const float*)d_in[0];
    const int*   edge_index   = (const int*)d_in[1];
    const float* edge_attr    = (const float*)d_in[2];
    const float* manual_gamma = (const float*)d_in[3];
    const float* manual_beta  = (const float*)d_in[4];
    const float* embed_W      = (const float*)d_in[5];
    const float* embed_b      = (const float*)d_in[6];
    const float* ln_gamma     = (const float*)d_in[7];
    const float* ln_beta      = (const float*)d_in[8];
    const float* lin_W        = (const float*)d_in[9];
    const float* lin_edge_W   = (const float*)d_in[10];
    const float* att_src      = (const float*)d_in[11];
    const float* att_dst      = (const float*)d_in[12];
    const float* att_edge     = (const float*)d_in[13];
    const float* gat_bias     = (const float*)d_in[14];
    const float* head_W1      = (const float*)d_in[15];
    const float* head_b1      = (const float*)d_in[16];
    const float* head_W2      = (const float*)d_in[17];
    const float* head_b2      = (const float*)d_in[18];
    float* out = (float*)d_out;

    const int* src = edge_index;
    const int* dst = edge_index + EE;

    char* ws = (char*)d_ws;
    size_t off = 0;
    auto alloc = [&](size_t bytes) {
        void* p = ws + off;
        off += (bytes + 255) & ~(size_t)255;
        return p;
    };
    int*   deg        = (int*)alloc(NN * 4);
    int*   row_ptr    = (int*)alloc((NN + 1) * 4);
    int*   cnt        = (int*)alloc(NN * 4);
    int2*  sedge      = (int2*)alloc((size_t)EE * 8);
    float* aeo        = (float*)alloc((size_t)LL * EE * 2 * 4);
    float* vbuf       = (float*)alloc(LL * 64 * 4);
    float* vs         = (float*)alloc(LL * 128 * 4);
    float* vvd        = (float*)alloc(LL * 128 * 4);
    float* hbuf       = (float*)alloc((size_t)NN * 64 * 4);
    float* a_s        = (float*)alloc((size_t)NN * 2 * 4);
    float* a_d        = (float*)alloc((size_t)NN * 2 * 4);
    unsigned short* Abf   = (unsigned short*)alloc((size_t)NN * 128 * 2);
    unsigned short* hm_bf = (unsigned short*)alloc((size_t)NN * 64 * 2);
    unsigned short* uvbuf = (unsigned short*)alloc((size_t)NN * 128 * 2);
    unsigned short* gBhi  = (unsigned short*)alloc((size_t)7 * 128 * 64 * 2);
    unsigned short* gBlo  = (unsigned short*)alloc((size_t)7 * 128 * 64 * 2);
    unsigned short* w1chi = (unsigned short*)alloc(64 * 32 * 2);
    unsigned short* w1clo = (unsigned short*)alloc(64 * 32 * 2);
    if (off > ws_size) return;  // insufficient workspace — fail visibly

    hipMemsetAsync(deg, 0, NN * 4, stream);
    hipMemsetAsync(cnt, 0, NN * 4, stream);

    deg_kernel<<<EE / 256, 256, 0, stream>>>(dst, deg);
    scan_kernel<<<1, 1024, 0, stream>>>(deg, row_ptr);
    fill_kernel<<<EE / 256, 256, 0, stream>>>(src, dst, row_ptr, cnt, sedge);
    vmake_kernel<<<1, 384, 0, stream>>>(lin_edge_W, att_edge, vbuf);
    ae_kernel<<<EE / 128, 128, 0, stream>>>(edge_attr, vbuf, aeo);
    vsmake_kernel<<<LL, 256, 0, stream>>>(lin_W, att_src, att_dst, vs, vvd);
    wprep_kernel<<<7, 256, 0, stream>>>(lin_W, head_W1, gBhi, gBlo);
    w1c_split_kernel<<<1, 256, 0, stream>>>(head_W1, w1chi, w1clo);
    embed_ln_kernel<<<NN / 4, 256, 0, stream>>>(x, embed_W, embed_b, ln_gamma, ln_beta,
                                                manual_gamma, manual_beta, vs, vvd,
                                                hm_bf, a_s, a_d);

    for (int l = 0; l < LL; ++l) {
        aggregate5_kernel<<<NN / 4, 256, 0, stream>>>(
            hm_bf, a_s, a_d, aeo + (size_t)l * EE * 2, row_ptr, sedge, Abf);
        if (l < LL - 1) {
            post_gemm<0><<<NN / 64, 256, 0, stream>>>(
                Abf, gBhi + (size_t)l * 128 * 64, gBlo + (size_t)l * 128 * 64,
                gat_bias + l * 64, ln_gamma + (l + 1) * 64, ln_beta + (l + 1) * 64,
                manual_gamma + (l + 1) * 64, manual_beta + (l + 1) * 64,
                vs + (l + 1) * 128, vvd + (l + 1) * 128, hm_bf, a_s, a_d, nullptr);
        } else {
            post_gemm<1><<<NN / 64, 256, 0, stream>>>(
                Abf, gBhi + (size_t)l * 128 * 64, gBlo + (size_t)l * 128 * 64,
                gat_bias + l * 64, nullptr, nullptr, nullptr, nullptr,
                nullptr, nullptr, nullptr, nullptr, nullptr, hbuf);
        }
    }

    uv_gemm<<<NN / 64, 256, 0, stream>>>(hbuf, gBhi + (size_t)6 * 128 * 64,
                                         gBlo + (size_t)6 * 128 * 64, uvbuf);
    head2_kernel<<<EE / 64, 256, 0, stream>>>(uvbuf, src, dst, edge_attr, w1chi, w1clo,
                                              head_b1, head_W2, head_b2, out);
}

// Round 9
// 511.996 us; speedup vs baseline: 1.0867x; 1.0156x over previous
//
#include <hip/hip_runtime.h>
#include <hip/hip_bf16.h>
#include <math.h>

#define NN 32768
#define EE 524288
#define LL 6

typedef __attribute__((ext_vector_type(8))) short short8;
typedef __attribute__((ext_vector_type(4))) float floatx4;

union U16x8 { short8 v; unsigned short u[8]; };

__device__ __forceinline__ unsigned short f2bf(float x) {
    union { float f; unsigned int u; } v; v.f = x;
    unsigned int r = v.u + 0x7fffu + ((v.u >> 16) & 1u);
    return (unsigned short)(r >> 16);
}
__device__ __forceinline__ float bf2f(unsigned short h) {
    union { unsigned int u; float f; } v; v.u = (unsigned int)h << 16;
    return v.f;
}

// ---------------- preprocessing ----------------

// row_ptr prefix sum; also zeroes cnt
__global__ __launch_bounds__(1024) void scan_kernel(const int* __restrict__ deg,
                                                    int* __restrict__ row_ptr,
                                                    int* __restrict__ cnt) {
    __shared__ int bs[1024];
    int t = threadIdx.x;
    int base = t * 32;
    int loc[32];
    int s = 0;
#pragma unroll
    for (int i = 0; i < 32; ++i) { int v = deg[base + i]; loc[i] = s; s += v; }
    bs[t] = s;
    __syncthreads();
    for (int off = 1; off < 1024; off <<= 1) {
        int v = (t >= off) ? bs[t - off] : 0;
        __syncthreads();
        bs[t] += v;
        __syncthreads();
    }
    int pre = (t == 0) ? 0 : bs[t - 1];
#pragma unroll
    for (int i = 0; i < 32; ++i) { row_ptr[base + i] = pre + loc[i]; cnt[base + i] = 0; }
    if (t == 1023) row_ptr[NN] = bs[1023];
}

__global__ void fill_kernel(const int* __restrict__ src, const int* __restrict__ dst,
                            const int* __restrict__ row_ptr, int* __restrict__ cnt,
                            int2* __restrict__ sedge) {
    int e = blockIdx.x * 256 + threadIdx.x;
    if (e >= EE) return;
    int d = dst[e];
    int pos = row_ptr[d] + atomicAdd(&cnt[d], 1);
    sedge[pos] = make_int2(src[e], e);
}

// One prep kernel: blocks 0..6 = wprep tiles; block 7 = vmake + w1c; blocks 8..13 = vsmake[l]
__global__ __launch_bounds__(256) void smallprep_kernel(
    const float* __restrict__ lin_W, const float* __restrict__ head_W1,
    const float* __restrict__ lin_edge_W, const float* __restrict__ att_edge,
    const float* __restrict__ att_src, const float* __restrict__ att_dst,
    unsigned short* __restrict__ gBhi, unsigned short* __restrict__ gBlo,
    float* __restrict__ vbuf, float* __restrict__ vs, float* __restrict__ vvd,
    unsigned short* __restrict__ w1chi, unsigned short* __restrict__ w1clo) {
    int bb = blockIdx.x;
    int tid = threadIdx.x;
    if (bb < 7) {
        unsigned short* dh = gBhi + (size_t)bb * 128 * 64;
        unsigned short* dl = gBlo + (size_t)bb * 128 * 64;
        if (bb < 6) {
            int n2 = tid & 63, kh = tid >> 6;
            U16x8 hh[4], ll[4];
            for (int kk = 0; kk < 32; ++kk) {
                int j = kh * 32 + kk;
                int h = j >> 6, k = j & 63;
                float wv = 0.5f * lin_W[((size_t)bb * 64 + k) * 128 + h * 64 + n2];
                unsigned short h16 = f2bf(wv);
                hh[kk >> 3].u[kk & 7] = h16;
                ll[kk >> 3].u[kk & 7] = f2bf(wv - bf2f(h16));
            }
#pragma unroll
            for (int c = 0; c < 4; ++c) {
                int cg = kh * 4 + c;
                int off = n2 * 128 + ((cg ^ (n2 & 15)) << 3);
                *(short8*)(dh + off) = hh[c].v;
                *(short8*)(dl + off) = ll[c].v;
            }
        } else {
            int n = tid & 127, kh = tid >> 7;
            U16x8 hh[4], ll[4];
            for (int kk = 0; kk < 32; ++kk) {
                int k = kh * 32 + kk;
                float wv = (n < 64) ? head_W1[k * 64 + n] : head_W1[(64 + k) * 64 + (n - 64)];
                unsigned short h16 = f2bf(wv);
                hh[kk >> 3].u[kk & 7] = h16;
                ll[kk >> 3].u[kk & 7] = f2bf(wv - bf2f(h16));
            }
#pragma unroll
            for (int c = 0; c < 4; ++c) {
                int cg = kh * 4 + c;
                int off = n * 64 + ((cg ^ (n & 7)) << 3);
                *(short8*)(dh + off) = hh[c].v;
                *(short8*)(dl + off) = ll[c].v;
            }
        }
    } else if (bb == 7) {
        // vmake: 384 entries
        for (int t = tid; t < 384; t += 256) {
            int l = t / 64; int r = t & 63; int ed = r >> 1; int hh = r & 1;
            const float* w = lin_edge_W + l * 32 * 128 + ed * 128 + hh * 64;
            const float* a = att_edge + l * 128 + hh * 64;
            float s = 0.f;
#pragma unroll 8
            for (int c = 0; c < 64; ++c) s += w[c] * a[c];
            vbuf[t] = s;
        }
        // w1c split
        int n = tid & 63, kc = tid >> 6;
#pragma unroll
        for (int j = 0; j < 8; ++j) {
            int k = kc * 8 + j;
            float wv = head_W1[(128 + k) * 64 + n];
            unsigned short h16 = f2bf(wv);
            w1chi[n * 32 + k] = h16;
            w1clo[n * 32 + k] = f2bf(wv - bf2f(h16));
        }
    } else {
        int l = bb - 8;
        int sel = tid >> 7, idx = tid & 127;
        int h = idx >> 6, k = idx & 63;
        const float* att = (sel ? att_dst : att_src) + l * 128 + h * 64;
        const float* wr = lin_W + ((size_t)l * 64 + k) * 128 + h * 64;
        float s = 0.f;
#pragma unroll 8
        for (int c = 0; c < 64; ++c) s += wr[c] * att[c];
        (sel ? vvd : vs)[l * 128 + idx] = s;
    }
}

// One edge-stream pass: a_e (all layers, original order) + degree atomics + bf16 edge_attr
__global__ void ae_deg_kernel(const float* __restrict__ edge_attr,
                              const int* __restrict__ dst,
                              const float* __restrict__ v,
                              float* __restrict__ aeo,
                              unsigned short* __restrict__ eabf,
                              int* __restrict__ deg) {
    __shared__ float sv[384];
    int tid = threadIdx.x;
    for (int i = tid; i < 384; i += 128) sv[i] = v[i];
    __syncthreads();
    int e = blockIdx.x * 128 + tid;
    if (e >= EE) return;
    atomicAdd(&deg[dst[e]], 1);
    float ea[32];
    const float4* p = (const float4*)(edge_attr + (size_t)e * 32);
#pragma unroll
    for (int i = 0; i < 8; ++i) {
        float4 f = p[i];
        ea[4 * i] = f.x; ea[4 * i + 1] = f.y; ea[4 * i + 2] = f.z; ea[4 * i + 3] = f.w;
    }
    // bf16 copy for the head
    U16x8 ub[4];
#pragma unroll
    for (int j = 0; j < 32; ++j) ub[j >> 3].u[j & 7] = f2bf(ea[j]);
#pragma unroll
    for (int j = 0; j < 4; ++j) *(short8*)(eabf + (size_t)e * 32 + j * 8) = ub[j].v;
#pragma unroll
    for (int l = 0; l < LL; ++l) {
        float s0 = 0.f, s1 = 0.f;
#pragma unroll
        for (int ed = 0; ed < 32; ++ed) {
            float x = ea[ed];
            s0 += x * sv[l * 64 + ed * 2];
            s1 += x * sv[l * 64 + ed * 2 + 1];
        }
        aeo[((size_t)l * EE + e) * 2] = s0;
        aeo[((size_t)l * EE + e) * 2 + 1] = s1;
    }
}

// embed + layer-0 LN/affine + layer-0 attention dots
__global__ __launch_bounds__(256) void embed_ln_kernel(
    const float* __restrict__ x, const float* __restrict__ W, const float* __restrict__ b,
    const float* __restrict__ ln_g, const float* __restrict__ ln_b,
    const float* __restrict__ mg, const float* __restrict__ mb,
    const float* __restrict__ vs0, const float* __restrict__ vd0,
    unsigned short* __restrict__ hm_bf, float* __restrict__ a_s, float* __restrict__ a_d) {
    __shared__ float xr[4][64];
    int w = threadIdx.x >> 6, j = threadIdx.x & 63;
    int n = blockIdx.x * 4 + w;
    xr[w][j] = x[(size_t)n * 64 + j];
    __syncthreads();
    float acc = b[j];
#pragma unroll 8
    for (int k = 0; k < 64; ++k) acc += xr[w][k] * W[k * 64 + j];
    float s = acc, sq = acc * acc;
    for (int off = 1; off < 64; off <<= 1) { s += __shfl_xor(s, off); sq += __shfl_xor(sq, off); }
    float mu = s * (1.f / 64.f);
    float var = sq * (1.f / 64.f) - mu * mu;
    float rs = rsqrtf(var + 1e-5f);
    float hm = mg[j] * (ln_g[j] * (acc - mu) * rs + ln_b[j]) + mb[j];
    hm_bf[(size_t)n * 64 + j] = f2bf(hm);
    float s0 = hm * vs0[j], s1 = hm * vs0[64 + j];
    float d0 = hm * vd0[j], d1 = hm * vd0[64 + j];
    for (int off = 1; off < 64; off <<= 1) {
        s0 += __shfl_xor(s0, off); s1 += __shfl_xor(s1, off);
        d0 += __shfl_xor(d0, off); d1 += __shfl_xor(d1, off);
    }
    if (j == 0) {
        a_s[n * 2] = s0; a_s[n * 2 + 1] = s1;
        a_d[n * 2] = d0; a_d[n * 2 + 1] = d1;
    }
}

// ---------------- GAT aggregation v6: pure-shfl broadcast, no LDS ----------------
__device__ __forceinline__ void fma8(uint4 pv, float w0, float w1, float* a0, float* a1) {
    unsigned int u[4] = {pv.x, pv.y, pv.z, pv.w};
#pragma unroll
    for (int j = 0; j < 4; ++j) {
        union { unsigned int q; float f; } lo, hi;
        lo.q = u[j] << 16; hi.q = u[j] & 0xffff0000u;
        a0[2 * j] += w0 * lo.f;  a1[2 * j] += w1 * lo.f;
        a0[2 * j + 1] += w0 * hi.f;  a1[2 * j + 1] += w1 * hi.f;
    }
}

__global__ __launch_bounds__(256) void aggregate6_kernel(
    const unsigned short* __restrict__ hm_bf, const float* __restrict__ a_s,
    const float* __restrict__ a_d, const float* __restrict__ aeo,
    const int* __restrict__ row_ptr, const int2* __restrict__ sedge,
    unsigned short* __restrict__ Abf) {
    int w = threadIdx.x >> 6, lane = threadIdx.x & 63;
    int n = blockIdx.x * 4 + w;
    int slot = lane >> 3, ch = lane & 7;
    const float2* as2 = (const float2*)a_s;
    const float2* ae2 = (const float2*)aeo;
    const uint4* hmv = (const uint4*)hm_bf;
    float2 adn = ((const float2*)a_d)[n];
    float2 asn = as2[n];
    uint4 pvself = hmv[(size_t)n * 8 + ch];
    int beg = row_ptr[n], end = row_ptr[n + 1];

    float acc0[8] = {}, acc1[8] = {};
    float den0 = 0.f, den1 = 0.f, aex = 0.f, aey = 0.f;

    for (int cs = beg; cs < end; cs += 64) {
        int cnt = min(64, end - cs);
        float w0v = 0.f, w1v = 0.f;
        int sval = n;
        if (lane < cnt) {
            int2 se = sedge[cs + lane];
            float2 ae = ae2[se.y];
            float2 as = as2[se.x];
            aex += ae.x; aey += ae.y;
            float al0 = as.x + adn.x + ae.x; al0 = al0 > 0.f ? al0 : 0.2f * al0;
            float al1 = as.y + adn.y + ae.y; al1 = al1 > 0.f ? al1 : 0.2f * al1;
            w0v = __expf(al0);
            w1v = __expf(al1);
            sval = se.x;
        }
        int ng2 = (cnt + 15) >> 4;
        for (int g2 = 0; g2 < ng2; ++g2) {
            int eA = g2 * 16 + slot, eB = eA + 8;
            int svA = __shfl(sval, eA), svB = __shfl(sval, eB);
            float wA0 = __shfl(w0v, eA), wA1 = __shfl(w1v, eA);
            float wB0 = __shfl(w0v, eB), wB1 = __shfl(w1v, eB);
            uint4 pvA = hmv[(size_t)svA * 8 + ch];
            uint4 pvB = hmv[(size_t)svB * 8 + ch];
            fma8(pvA, wA0, wA1, acc0, acc1);
            den0 += wA0; den1 += wA1;
            fma8(pvB, wB0, wB1, acc0, acc1);
            den0 += wB0; den1 += wB1;
        }
    }
    // full-lane sum for aex/aey (edge index = lane, all 6 bits)
    for (int m = 1; m < 8; m <<= 1) {
        aex += __shfl_xor(aex, m);
        aey += __shfl_xor(aey, m);
    }
#pragma unroll
    for (int m = 8; m < 64; m <<= 1) {
#pragma unroll
        for (int j = 0; j < 8; ++j) {
            acc0[j] += __shfl_xor(acc0[j], m);
            acc1[j] += __shfl_xor(acc1[j], m);
        }
        den0 += __shfl_xor(den0, m);
        den1 += __shfl_xor(den1, m);
        aex += __shfl_xor(aex, m);
        aey += __shfl_xor(aey, m);
    }
    if (slot == 0) {
        float invd = 1.f / fmaxf((float)(end - beg), 1.f);
        float al0 = asn.x + adn.x + aex * invd; al0 = al0 > 0.f ? al0 : 0.2f * al0;
        float al1 = asn.y + adn.y + aey * invd; al1 = al1 > 0.f ? al1 : 0.2f * al1;
        float ws0 = __expf(al0), ws1 = __expf(al1);
        fma8(pvself, ws0, ws1, acc0, acc1);
        den0 += ws0; den1 += ws1;
        float inv0 = 1.f / (den0 + 1e-16f), inv1 = 1.f / (den1 + 1e-16f);
        U16x8 h0, h1;
#pragma unroll
        for (int j = 0; j < 8; ++j) {
            h0.u[j] = f2bf(acc0[j] * inv0);
            h1.u[j] = f2bf(acc1[j] * inv1);
        }
        int i15 = n & 15;
        unsigned short* row = Abf + (size_t)n * 128;
        *(short8*)(row + ((ch ^ i15) << 3)) = h0.v;
        *(short8*)(row + (((8 + ch) ^ i15) << 3)) = h1.v;
    }
}

// ---------------- post-aggregation GEMM (layers 0..4): fuses next-layer LN + att dots ----
__global__ __launch_bounds__(256) void post_gemm(
    const unsigned short* __restrict__ Abf, const unsigned short* __restrict__ gBhi,
    const unsigned short* __restrict__ gBlo, const float* __restrict__ bias,
    const float* __restrict__ ln_g, const float* __restrict__ ln_b,
    const float* __restrict__ mg, const float* __restrict__ mb,
    const float* __restrict__ vsn, const float* __restrict__ vdn,
    unsigned short* __restrict__ hm_bf, float* __restrict__ a_s, float* __restrict__ a_d) {
    __shared__ unsigned short Ahi[64 * 128];
    __shared__ unsigned short Bhi[64 * 128], Blo[64 * 128];
    int tid = threadIdx.x;
    {
        const uint4* sa = (const uint4*)(Abf + (size_t)blockIdx.x * 64 * 128);
        const uint4* sh = (const uint4*)gBhi;
        const uint4* sl = (const uint4*)gBlo;
        for (int i = tid; i < 1024; i += 256) {
            ((uint4*)Ahi)[i] = sa[i];
            ((uint4*)Bhi)[i] = sh[i];
            ((uint4*)Blo)[i] = sl[i];
        }
    }
    __syncthreads();

    int w = tid >> 6, lane = tid & 63, col = lane & 15, quad = lane >> 4;
    int m = w * 16 + col;
    floatx4 acc[4] = {};
#pragma unroll
    for (int s = 0; s < 4; ++s) {
        int ca = (quad + 4 * s) ^ col;
        short8 ahi = *(const short8*)(Ahi + m * 128 + ca * 8);
#pragma unroll
        for (int t = 0; t < 4; ++t) {
            int off = (t * 16 + col) * 128 + ca * 8;
            short8 bhi = *(const short8*)(Bhi + off);
            short8 blo = *(const short8*)(Blo + off);
            acc[t] = __builtin_amdgcn_mfma_f32_16x16x32_bf16(ahi, blo, acc[t], 0, 0, 0);
            acc[t] = __builtin_amdgcn_mfma_f32_16x16x32_bf16(ahi, bhi, acc[t], 0, 0, 0);
        }
    }
    int nodebase = blockIdx.x * 64 + w * 16;
    float bv[4];
#pragma unroll
    for (int t = 0; t < 4; ++t) bv[t] = bias[t * 16 + col];
    float vsv[4], vsv1[4], vdv[4], vdv1[4], lg[4], lb[4], mgv[4], mbv[4];
#pragma unroll
    for (int t = 0; t < 4; ++t) {
        int c = t * 16 + col;
        vsv[t] = vsn[c]; vsv1[t] = vsn[64 + c];
        vdv[t] = vdn[c]; vdv1[t] = vdn[64 + c];
        lg[t] = ln_g[c]; lb[t] = ln_b[c];
        mgv[t] = mg[c]; mbv[t] = mb[c];
    }
#pragma unroll
    for (int r = 0; r < 4; ++r) {
        int node = nodebase + quad * 4 + r;
        float hv[4];
        float s = 0.f, sq = 0.f;
#pragma unroll
        for (int t = 0; t < 4; ++t) {
            float v = acc[t][r] + bv[t];
            v = v > 0.f ? v : 0.f;
            hv[t] = v;
            s += v; sq += v * v;
        }
        for (int off = 1; off < 16; off <<= 1) { s += __shfl_xor(s, off); sq += __shfl_xor(sq, off); }
        float mu = s * (1.f / 64.f);
        float var = sq * (1.f / 64.f) - mu * mu;
        float rs = rsqrtf(var + 1e-5f);
        float s0 = 0.f, s1 = 0.f, d0 = 0.f, d1 = 0.f;
#pragma unroll
        for (int t = 0; t < 4; ++t) {
            float hmv = mgv[t] * (lg[t] * (hv[t] - mu) * rs + lb[t]) + mbv[t];
            hm_bf[(size_t)node * 64 + t * 16 + col] = f2bf(hmv);
            s0 += hmv * vsv[t]; s1 += hmv * vsv1[t];
            d0 += hmv * vdv[t]; d1 += hmv * vdv1[t];
        }
        for (int off = 1; off < 16; off <<= 1) {
            s0 += __shfl_xor(s0, off); s1 += __shfl_xor(s1, off);
            d0 += __shfl_xor(d0, off); d1 += __shfl_xor(d1, off);
        }
        if (col == 0) {
            a_s[node * 2] = s0; a_s[node * 2 + 1] = s1;
            a_d[node * 2] = d0; a_d[node * 2 + 1] = d1;
        }
    }
}

// ---------------- fused last layer: h = relu(A@B5+bias); uv = [h.W1a | h.W1b] ----------------
__global__ __launch_bounds__(256) void postuv_gemm(
    const unsigned short* __restrict__ Abf, const unsigned short* __restrict__ gB5hi,
    const unsigned short* __restrict__ gB5lo, const float* __restrict__ bias,
    const unsigned short* __restrict__ gB6hi, const unsigned short* __restrict__ gB6lo,
    unsigned short* __restrict__ uv) {
    __shared__ unsigned short lds[24576];  // 48 KB
    unsigned short* Ahi  = lds;            // stage1 A: 64x128
    unsigned short* B5hi = lds + 8192;     // stage1 B: 64x128
    unsigned short* B5lo = lds + 16384;
    unsigned short* A2hi = lds;            // stage2 A: 64x64 (aliases Ahi)
    unsigned short* A2lo = lds + 4096;
    unsigned short* B6hi = lds + 8192;     // stage2 B: 128x64 (aliases B5hi)
    unsigned short* B6lo = lds + 16384;
    int tid = threadIdx.x;
    {
        const uint4* sa = (const uint4*)(Abf + (size_t)blockIdx.x * 64 * 128);
        const uint4* sh = (const uint4*)gB5hi;
        const uint4* sl = (const uint4*)gB5lo;
        for (int i = tid; i < 1024; i += 256) {
            ((uint4*)Ahi)[i] = sa[i];
            ((uint4*)B5hi)[i] = sh[i];
            ((uint4*)B5lo)[i] = sl[i];
        }
    }
    __syncthreads();

    int w = tid >> 6, lane = tid & 63, col = lane & 15, quad = lane >> 4;
    int m = w * 16 + col;
    floatx4 acc[4] = {};
#pragma unroll
    for (int s = 0; s < 4; ++s) {
        int ca = (quad + 4 * s) ^ col;
        short8 ahi = *(const short8*)(Ahi + m * 128 + ca * 8);
#pragma unroll
        for (int t = 0; t < 4; ++t) {
            int off = (t * 16 + col) * 128 + ca * 8;
            short8 bhi = *(const short8*)(B5hi + off);
            short8 blo = *(const short8*)(B5lo + off);
            acc[t] = __builtin_amdgcn_mfma_f32_16x16x32_bf16(ahi, blo, acc[t], 0, 0, 0);
            acc[t] = __builtin_amdgcn_mfma_f32_16x16x32_bf16(ahi, bhi, acc[t], 0, 0, 0);
        }
    }
    float bv[4];
#pragma unroll
    for (int t = 0; t < 4; ++t) bv[t] = bias[t * 16 + col];
    __syncthreads();  // stage1 LDS fully consumed
    // write h (hi/lo bf16) into stage2 A layout; copy B6 (1024 uint4 per buffer!)
#pragma unroll
    for (int t = 0; t < 4; ++t) {
        int c = t * 16 + col;
        int cg = c >> 3, cr = c & 7;
#pragma unroll
        for (int r = 0; r < 4; ++r) {
            float v = acc[t][r] + bv[t];
            v = v > 0.f ? v : 0.f;
            int i = w * 16 + quad * 4 + r;
            int off = i * 64 + ((cg ^ (i & 7)) << 3) + cr;
            unsigned short hh = f2bf(v);
            A2hi[off] = hh;
            A2lo[off] = f2bf(v - bf2f(hh));
        }
    }
    for (int i = tid; i < 1024; i += 256) {
        ((uint4*)B6hi)[i] = ((const uint4*)gB6hi)[i];
        ((uint4*)B6lo)[i] = ((const uint4*)gB6lo)[i];
    }
    __syncthreads();

    floatx4 acc2[8] = {};
#pragma unroll
    for (int s = 0; s < 2; ++s) {
        int ca = (quad + 4 * s) ^ (col & 7);
        short8 a2h = *(const short8*)(A2hi + m * 64 + ca * 8);
        short8 a2l = *(const short8*)(A2lo + m * 64 + ca * 8);
#pragma unroll
        for (int t = 0; t < 8; ++t) {
            int off = (t * 16 + col) * 64 + ca * 8;
            short8 bh = *(const short8*)(B6hi + off);
            short8 bl = *(const short8*)(B6lo + off);
            acc2[t] = __builtin_amdgcn_mfma_f32_16x16x32_bf16(a2l, bh, acc2[t], 0, 0, 0);
            acc2[t] = __builtin_amdgcn_mfma_f32_16x16x32_bf16(a2h, bl, acc2[t], 0, 0, 0);
            acc2[t] = __builtin_amdgcn_mfma_f32_16x16x32_bf16(a2h, bh, acc2[t], 0, 0, 0);
        }
    }
    int nodebase = blockIdx.x * 64 + w * 16;
#pragma unroll
    for (int t = 0; t < 8; ++t)
#pragma unroll
        for (int r = 0; r < 4; ++r)
            uv[(size_t)(nodebase + quad * 4 + r) * 128 + t * 16 + col] = f2bf(acc2[t][r]);
}

// ---------------- edge output head (bf16 edge_attr) ----------------
__global__ __launch_bounds__(256) void head2_kernel(
    const unsigned short* __restrict__ uv, const int* __restrict__ src,
    const int* __restrict__ dst, const unsigned short* __restrict__ eabf,
    const unsigned short* __restrict__ w1chi, const unsigned short* __restrict__ w1clo,
    const float* __restrict__ b1, const float* __restrict__ W2,
    const float* __restrict__ b2, float* __restrict__ out) {
    __shared__ float g[64][68];
    __shared__ unsigned short Abf[64 * 40];
    __shared__ unsigned short Bh[64 * 40], Bl[64 * 40];
    __shared__ int sA[64], dA[64];
    int tid = threadIdx.x;
    int base = blockIdx.x * 64;
    if (tid < 64) sA[tid] = src[base + tid];
    else if (tid < 128) dA[tid - 64] = dst[base + tid - 64];
    {
        int n = tid >> 2, c = tid & 3;
        *(short8*)(Bh + n * 40 + c * 8) = *(const short8*)(w1chi + n * 32 + c * 8);
        *(short8*)(Bl + n * 40 + c * 8) = *(const short8*)(w1clo + n * 32 + c * 8);
    }
    {
        int e = tid >> 2, q = tid & 3;
        *(short8*)(Abf + e * 40 + q * 8) = *(const short8*)(eabf + (size_t)(base + e) * 32 + q * 8);
    }
    __syncthreads();
    {
        int e = tid >> 2, q = tid & 3;
        const uint4* su = (const uint4*)(uv + (size_t)sA[e] * 128);
        const uint4* dv = (const uint4*)(uv + (size_t)dA[e] * 128);
        uint4 U0 = su[2 * q], U1 = su[2 * q + 1];
        uint4 V0 = dv[8 + 2 * q], V1 = dv[9 + 2 * q];
        const float4* b1p = (const float4*)(b1 + q * 16);
        float bb[16];
#pragma unroll
        for (int j = 0; j < 4; ++j) {
            float4 b4 = b1p[j];
            bb[4 * j] = b4.x; bb[4 * j + 1] = b4.y; bb[4 * j + 2] = b4.z; bb[4 * j + 3] = b4.w;
        }
        unsigned int uw[8] = {U0.x, U0.y, U0.z, U0.w, U1.x, U1.y, U1.z, U1.w};
        unsigned int vw[8] = {V0.x, V0.y, V0.z, V0.w, V1.x, V1.y, V1.z, V1.w};
        float* gr = &g[e][q * 16];
#pragma unroll
        for (int j = 0; j < 8; ++j) {
            gr[2 * j] = bf2f((unsigned short)(uw[j] & 0xffff)) +
                        bf2f((unsigned short)(vw[j] & 0xffff)) + bb[2 * j];
            gr[2 * j + 1] = bf2f((unsigned short)(uw[j] >> 16)) +
                            bf2f((unsigned short)(vw[j] >> 16)) + bb[2 * j + 1];
        }
    }
    __syncthreads();

    int lane = tid & 63, w = tid >> 6, col = lane & 15, quad = lane >> 4;
    short8 a = *(const short8*)(Abf + (w * 16 + col) * 40 + quad * 8);
    floatx4 acc[4] = {};
#pragma unroll
    for (int t = 0; t < 4; ++t) {
        int off = (t * 16 + col) * 40 + quad * 8;
        short8 bh = *(const short8*)(Bh + off);
        short8 bl = *(const short8*)(Bl + off);
        acc[t] = __builtin_amdgcn_mfma_f32_16x16x32_bf16(a, bl, acc[t], 0, 0, 0);
        acc[t] = __builtin_amdgcn_mfma_f32_16x16x32_bf16(a, bh, acc[t], 0, 0, 0);
    }
    float sv[4] = {0.f, 0.f, 0.f, 0.f};
#pragma unroll
    for (int t = 0; t < 4; ++t) {
        float w2v = W2[t * 16 + col];
#pragma unroll
        for (int r = 0; r < 4; ++r) {
            float hid = acc[t][r] + g[w * 16 + quad * 4 + r][t * 16 + col];
            hid = hid > 0.f ? hid : 0.f;
            sv[r] += hid * w2v;
        }
    }
    float b2v = b2[0];
#pragma unroll
    for (int r = 0; r < 4; ++r) {
        float v = sv[r];
        v += __shfl_xor(v, 1);
        v += __shfl_xor(v, 2);
        v += __shfl_xor(v, 4);
        v += __shfl_xor(v, 8);
        if (col == 0) out[base + w * 16 + quad * 4 + r] = v + b2v;
    }
}

// ---------------- launch ----------------

extern "C" void kernel_launch(void* const* d_in, const int* in_sizes, int n_in,
                              void* d_out, int out_size, void* d_ws, size_t ws_size,
                              hipStream_t stream) {
    const float* x            = (const float*)d_in[0];
    const int*   edge_index   = (const int*)d_in[1];
    const float* edge_attr    = (const float*)d_in[2];
    const float* manual_gamma = (const float*)d_in[3];
    const float* manual_beta  = (const float*)d_in[4];
    const float* embed_W      = (const float*)d_in[5];
    const float* embed_b      = (const float*)d_in[6];
    const float* ln_gamma     = (const float*)d_in[7];
    const float* ln_beta      = (const float*)d_in[8];
    const float* lin_W        = (const float*)d_in[9];
    const float* lin_edge_W   = (const float*)d_in[10];
    const float* att_src      = (const float*)d_in[11];
    const float* att_dst      = (const float*)d_in[12];
    const float* att_edge     = (const float*)d_in[13];
    const float* gat_bias     = (const float*)d_in[14];
    const float* head_W1      = (const float*)d_in[15];
    const float* head_b1      = (const float*)d_in[16];
    const float* head_W2      = (const float*)d_in[17];
    const float* head_b2      = (const float*)d_in[18];
    float* out = (float*)d_out;

    const int* src = edge_index;
    const int* dst = edge_index + EE;

    char* ws = (char*)d_ws;
    size_t off = 0;
    auto alloc = [&](size_t bytes) {
        void* p = ws + off;
        off += (bytes + 255) & ~(size_t)255;
        return p;
    };
    int*   deg        = (int*)alloc(NN * 4);
    int*   row_ptr    = (int*)alloc((NN + 1) * 4);
    int*   cnt        = (int*)alloc(NN * 4);
    int2*  sedge      = (int2*)alloc((size_t)EE * 8);
    float* aeo        = (float*)alloc((size_t)LL * EE * 2 * 4);
    float* vbuf       = (float*)alloc(LL * 64 * 4);
    float* vs         = (float*)alloc(LL * 128 * 4);
    float* vvd        = (float*)alloc(LL * 128 * 4);
    float* a_s        = (float*)alloc((size_t)NN * 2 * 4);
    float* a_d        = (float*)alloc((size_t)NN * 2 * 4);
    unsigned short* Abf   = (unsigned short*)alloc((size_t)NN * 128 * 2);
    unsigned short* hm_bf = (unsigned short*)alloc((size_t)NN * 64 * 2);
    unsigned short* uvbuf = (unsigned short*)alloc((size_t)NN * 128 * 2);
    unsigned short* eabf  = (unsigned short*)alloc((size_t)EE * 32 * 2);
    unsigned short* gBhi  = (unsigned short*)alloc((size_t)7 * 128 * 64 * 2);
    unsigned short* gBlo  = (unsigned short*)alloc((size_t)7 * 128 * 64 * 2);
    unsigned short* w1chi = (unsigned short*)alloc(64 * 32 * 2);
    unsigned short* w1clo = (unsigned short*)alloc(64 * 32 * 2);
    if (off > ws_size) return;  // insufficient workspace — fail visibly

    hipMemsetAsync(deg, 0, NN * 4, stream);

    smallprep_kernel<<<14, 256, 0, stream>>>(lin_W, head_W1, lin_edge_W, att_edge,
                                             att_src, att_dst, gBhi, gBlo, vbuf,
                                             vs, vvd, w1chi, w1clo);
    ae_deg_kernel<<<EE / 128, 128, 0, stream>>>(edge_attr, dst, vbuf, aeo, eabf, deg);
    scan_kernel<<<1, 1024, 0, stream>>>(deg, row_ptr, cnt);
    fill_kernel<<<EE / 256, 256, 0, stream>>>(src, dst, row_ptr, cnt, sedge);
    embed_ln_kernel<<<NN / 4, 256, 0, stream>>>(x, embed_W, embed_b, ln_gamma, ln_beta,
                                                manual_gamma, manual_beta, vs, vvd,
                                                hm_bf, a_s, a_d);

    for (int l = 0; l < LL; ++l) {
        aggregate6_kernel<<<NN / 4, 256, 0, stream>>>(
            hm_bf, a_s, a_d, aeo + (size_t)l * EE * 2, row_ptr, sedge, Abf);
        if (l < LL - 1) {
            post_gemm<<<NN / 64, 256, 0, stream>>>(
                Abf, gBhi + (size_t)l * 128 * 64, gBlo + (size_t)l * 128 * 64,
                gat_bias + l * 64, ln_gamma + (l + 1) * 64, ln_beta + (l + 1) * 64,
                manual_gamma + (l + 1) * 64, manual_beta + (l + 1) * 64,
                vs + (l + 1) * 128, vvd + (l + 1) * 128, hm_bf, a_s, a_d);
        } else {
            postuv_gemm<<<NN / 64, 256, 0, stream>>>(
                Abf, gBhi + (size_t)l * 128 * 64, gBlo + (size_t)l * 128 * 64,
                gat_bias + l * 64, gBhi + (size_t)6 * 128 * 64,
                gBlo + (size_t)6 * 128 * 64, uvbuf);
        }
    }

    head2_kernel<<<EE / 64, 256, 0, stream>>>(uvbuf, src, dst, eabf, w1chi, w1clo,
                                              head_b1, head_W2, head_b2, out);
}